// Round 3
// baseline (305.159 us; speedup 1.0000x reference)
//
#include <hip/hip_runtime.h>
#include <hip/hip_bf16.h>
#include <stdint.h>

// ---------------------------------------------------------------------------
// fp32 inputs; mask int32; fp32 output. Internal pipeline bf16/f16.
// LayerNorm -> fused {q,kv} proj GEMMs with l2norm epilogues (V emitted f16
//   TRANSPOSED [b,h][d][token], null token at column 2048, zero pad 2049..55)
//   -> flash attn: S^T = K.Q^T (16x16x32 bf16) with PERMUTED K-token rows so
//      exp(S^T) packs straight into the A-operand of 16x16x32 f16 PV MFMAs;
//      mask applied as 0/-512 bias in the QK C-initializer -> out proj.
// R12: GEMM K-loop restructured to the T3-minimum 2-phase pipeline:
//      double-buffered LDS (2x16KB), next-tile global_load_lds issued BEFORE
//      computing the current tile, ONE __syncthreads per K-step (was 2 full
//      vmcnt(0) drains per step with zero overlap -> at K=1024 the 64 drains
//      per block were the dominant GEMM stall; now the prefetch has the whole
//      ~250cyc compute phase to land before the single drain).
//      attn/LN/transpose/nullkv unchanged (R11-verified).
// ---------------------------------------------------------------------------

using f32x4  = __attribute__((ext_vector_type(4))) float;
using bf16x8 = __attribute__((ext_vector_type(8))) __bf16;
using f16x8  = __attribute__((ext_vector_type(8))) _Float16;
using uintv4 = __attribute__((ext_vector_type(4))) unsigned int;

__device__ __forceinline__ float b2f(unsigned short u) {
    return __uint_as_float(((unsigned)u) << 16);
}
__device__ __forceinline__ unsigned short f2b(float f) {
    unsigned u = __float_as_uint(f);
    u += 0x7fffu + ((u >> 16) & 1u);   // RNE
    return (unsigned short)(u >> 16);
}
__device__ __forceinline__ unsigned short f2h(float f) {   // RNE f32->f16
    return __builtin_bit_cast(unsigned short, (_Float16)f);
}
__device__ __forceinline__ f32x4 mfma16(bf16x8 a, bf16x8 b, f32x4 c) {
    return __builtin_amdgcn_mfma_f32_16x16x32_bf16(a, b, c, 0, 0, 0);
}
__device__ __forceinline__ f32x4 mfma16h(f16x8 a, f16x8 b, f32x4 c) {
    return __builtin_amdgcn_mfma_f32_16x16x32_f16(a, b, c, 0, 0, 0);
}
// packed f32x2 -> f16x2 (RTZ), returned as the raw 32-bit pattern
__device__ __forceinline__ unsigned pk16(float a, float b) {
    return __builtin_bit_cast(unsigned, __builtin_amdgcn_cvt_pkrtz(a, b));
}
// async global->LDS, 16B/lane; LDS dst = wave-uniform base + lane*16
__device__ __forceinline__ void gl_lds16(const void* g, void* l) {
    __builtin_amdgcn_global_load_lds(
        (const __attribute__((address_space(1))) unsigned int*)g,
        (__attribute__((address_space(3))) unsigned int*)l, 16, 0, 0);
}

// ------------- weight transpose + fp32->bf16: in[R][C] -> out[C][R] --------
__global__ __launch_bounds__(256) void transpose_f2b(
    const float* __restrict__ in, unsigned short* __restrict__ out,
    int R, int C)
{
    __shared__ unsigned short t[32][33];
    int tx = threadIdx.x, ty = threadIdx.y;       // (32,8)
    int c = blockIdx.x * 32 + tx;
#pragma unroll
    for (int i = 0; i < 4; ++i) {
        int r = blockIdx.y * 32 + ty + i * 8;
        t[ty + i * 8][tx] = f2b(in[(size_t)r * C + c]);
    }
    __syncthreads();
    int r2 = blockIdx.y * 32 + tx;
#pragma unroll
    for (int i = 0; i < 4; ++i) {
        int c2 = blockIdx.x * 32 + ty + i * 8;
        out[(size_t)c2 * R + r2] = t[tx][ty + i * 8];
    }
}

// -------- LayerNorm: one row (1024 fp32) per block of 256 -> bf16 ----------
__global__ __launch_bounds__(256) void ln_kernel(
    const float* __restrict__ x, const float* __restrict__ gamma,
    unsigned short* __restrict__ xn)
{
    int row = blockIdx.x, tid = threadIdx.x;
    int wave = tid >> 6, lane = tid & 63;
    float4 raw = *(const float4*)(x + ((size_t)row << 10) + (tid << 2));
    float v[4] = { raw.x, raw.y, raw.z, raw.w };
    float s  = v[0] + v[1] + v[2] + v[3];
    float s2 = v[0]*v[0] + v[1]*v[1] + v[2]*v[2] + v[3]*v[3];
#pragma unroll
    for (int off = 1; off < 64; off <<= 1) {
        s  += __shfl_xor(s, off);
        s2 += __shfl_xor(s2, off);
    }
    __shared__ float ps[4], ps2[4], sh[2];
    if (lane == 0) { ps[wave] = s; ps2[wave] = s2; }
    __syncthreads();
    if (tid == 0) {
        float S  = ps[0] + ps[1] + ps[2] + ps[3];
        float S2 = ps2[0] + ps2[1] + ps2[2] + ps2[3];
        float mu  = S * (1.f / 1024.f);
        float var = S2 * (1.f / 1024.f) - mu * mu;
        sh[0] = mu; sh[1] = rsqrtf(var + 1e-5f);
    }
    __syncthreads();
    float mu = sh[0], rstd = sh[1];
    float4 g4 = *(const float4*)(gamma + (tid << 2));
    float g[4] = { g4.x, g4.y, g4.z, g4.w };
    unsigned short o[4];
#pragma unroll
    for (int i = 0; i < 4; ++i) o[i] = f2b((v[i] - mu) * rstd * g[i]);
    uint2 out;
    out.x = (unsigned)o[0] | ((unsigned)o[1] << 16);
    out.y = (unsigned)o[2] | ((unsigned)o[3] << 16);
    *(uint2*)(xn + ((size_t)row << 10) + (tid << 2)) = out;
}

// ---- GEMM C[M,N]=A[M,K]*Bt[N,K]^T, 128x128, dbuf gl_lds staging ----------
// 2-phase pipeline: stage(next tile, other buf) -> compute(cur) -> 1 barrier.
// MODE 0 (QNORM): per-head l2norm rows + q_scale*0.125*log2e, bf16 out
// MODE 1 (KV):    cols<1024: l2norm + k_scale, bf16 -> Cout (ldc=1024);
//                 cols>=1024: raw f16 TRANSPOSED -> Vout[b*16+h][d][tok]
//                 (row stride 2056 halfs) via per-wave LDS transpose,
//                 contiguous uint2 stores.
// MODE 2 (F32):   plain f32 store
template<int MODE>
__global__ __launch_bounds__(256, 2) void gemm_bt(
    const unsigned short* __restrict__ A, const unsigned short* __restrict__ Bt,
    void* __restrict__ Cout, const float* __restrict__ scale,
    unsigned short* __restrict__ Vout,
    int M, int N, int K, int ldc)
{
    __shared__ __bf16 As[2][128 * 32];
    __shared__ __bf16 Bs[2][128 * 32];
    int tid = threadIdx.x, lane = tid & 63, wave = tid >> 6;
    int quad = lane >> 4, l15 = lane & 15;
    int m0 = blockIdx.y * 128, n0 = blockIdx.x * 128;
    int wm = (wave & 1) * 64, wn = (wave >> 1) * 64;
    f32x4 acc[4][4] = {};

    const int srow = wave * 32 + (lane >> 2);
    const int scol = (lane & 3) << 3;
    const unsigned short* gA = A  + (size_t)(m0 + srow) * K + scol;
    const unsigned short* gB = Bt + (size_t)(n0 + srow) * K + scol;
    const size_t rstep = (size_t)16 * K;
    const int lo0 = (wave * 32) * 32;
    const int lo1 = (wave * 32 + 16) * 32;

    auto stage = [&](int bf) {
        gl_lds16(gA,         &As[bf][lo0]);
        gl_lds16(gA + rstep, &As[bf][lo1]);
        gl_lds16(gB,         &Bs[bf][lo0]);
        gl_lds16(gB + rstep, &Bs[bf][lo1]);
        gA += 32; gB += 32;
    };

    stage(0);
    __syncthreads();                       // tile 0 resident
    const int nsteps = K >> 5;
    for (int s = 0; s < nsteps; ++s) {
        const int cur = s & 1;
        if (s + 1 < nsteps) stage(cur ^ 1);   // prefetch overlaps compute
        bf16x8 af[4], bfv[4];
#pragma unroll
        for (int i = 0; i < 4; ++i)
            af[i] = *(const bf16x8*)&As[cur][(wm + i * 16 + l15) * 32 + quad * 8];
#pragma unroll
        for (int j = 0; j < 4; ++j)
            bfv[j] = *(const bf16x8*)&Bs[cur][(wn + j * 16 + l15) * 32 + quad * 8];
#pragma unroll
        for (int i = 0; i < 4; ++i)
#pragma unroll
            for (int j = 0; j < 4; ++j)
                acc[i][j] = mfma16(af[i], bfv[j], acc[i][j]);
        __syncthreads();   // drains prefetch (had full compute to land) +
    }                      // guarantees cur's readers done before next write

    if (MODE == 2) {
#pragma unroll
        for (int i = 0; i < 4; ++i)
#pragma unroll
            for (int j = 0; j < 4; ++j) {
                int row = m0 + wm + i * 16 + quad * 4;
                int col = n0 + wn + j * 16 + l15;
                size_t base = (size_t)row * ldc + col;
#pragma unroll
                for (int r = 0; r < 4; ++r)
                    ((float*)Cout)[base + (size_t)r * ldc] = acc[i][j][r];
            }
        return;
    }

    // wave's 64 cols (wn + j*16 + l15) = exactly one head; head-dim = j*16+l15
    if constexpr (MODE == 1) {
        const bool isv = (n0 + wn) >= 1024;
        if (isv) {
            // per-wave 64x64 (tok x d) tile -> LDS transposed with XOR
            // swizzle tok^((d&7)<<3) -> contiguous uint2 global stores.
            __shared__ unsigned short Vx[4][64 * 64];   // 32 KB (MODE 1 only)
            unsigned short* tileL = Vx[wave];
            int hv = (n0 + wn - 1024) >> 6;
            int bidx = m0 >> 11;                        // block never straddles
            int tok0w = (m0 + wm) & 2047;
            size_t vbase = (size_t)((((bidx << 4) + hv) << 6)) * 2056;
#pragma unroll
            for (int i = 0; i < 4; ++i)
#pragma unroll
                for (int j = 0; j < 4; ++j) {
                    int d = j * 16 + l15;
                    int tk = (i * 16 + quad * 4) ^ ((d & 7) << 3);
                    unsigned u01 = (unsigned)f2h(acc[i][j][0])
                                 | ((unsigned)f2h(acc[i][j][1]) << 16);
                    unsigned u23 = (unsigned)f2h(acc[i][j][2])
                                 | ((unsigned)f2h(acc[i][j][3]) << 16);
                    *(unsigned*)&tileL[d * 64 + tk]     = u01;
                    *(unsigned*)&tileL[d * 64 + tk + 2] = u23;
                }
            // same-wave read-out (compiler orders via lgkmcnt)
#pragma unroll
            for (int rr = 0; rr < 16; ++rr) {
                int d = rr * 4 + quad;
                uint2 val = *(const uint2*)
                    &tileL[d * 64 + ((l15 * 4) ^ ((d & 7) << 3))];
                *(uint2*)(Vout + vbase + (size_t)d * 2056 + tok0w + l15 * 4) = val;
            }
            return;
        }
    }

    float sc[4];
#pragma unroll
    for (int j = 0; j < 4; ++j) {
        float s = scale[j * 16 + l15];
        sc[j] = (MODE == 0) ? s * (0.125f * 1.44269504088896f) : s;
    }
#pragma unroll
    for (int i = 0; i < 4; ++i)
#pragma unroll
        for (int r = 0; r < 4; ++r) {
            float ss = 0.f;
#pragma unroll
            for (int j = 0; j < 4; ++j) ss += acc[i][j][r] * acc[i][j][r];
            ss += __shfl_xor(ss, 1); ss += __shfl_xor(ss, 2);
            ss += __shfl_xor(ss, 4); ss += __shfl_xor(ss, 8);
            float mul = rsqrtf(ss + 1e-12f);
            size_t rowbase = (size_t)(m0 + wm + i * 16 + quad * 4 + r) * ldc
                           + n0 + wn + l15;
#pragma unroll
            for (int j = 0; j < 4; ++j) {
                float v = acc[i][j][r];
                ((unsigned short*)Cout)[rowbase + j * 16] = f2b(v * mul * sc[j]);
            }
        }
}

// -- null kv: l2norm k + k_scale (bf16); v -> VtG col 2048; zero 2049..2055 -
// Runs AFTER gemm<0> (WqT, overlapped into VtG tail, is dead by then).
__global__ __launch_bounds__(256) void nullkv_kernel(
    const float* __restrict__ null_kv, const float* __restrict__ k_scale,
    unsigned short* __restrict__ knull, unsigned short* __restrict__ Vt)
{
    int wave = threadIdx.x >> 6, lane = threadIdx.x & 63;
    int h = blockIdx.x * 4 + wave;
    int idx = (h << 6) + lane;
    float kvl = null_kv[idx];
    float ss = kvl * kvl;
#pragma unroll
    for (int off = 1; off < 64; off <<= 1) ss += __shfl_xor(ss, off);
    knull[idx] = f2b(kvl * rsqrtf(ss + 1e-12f) * k_scale[lane]);
    unsigned short vn = f2h(null_kv[1024 + idx]);
#pragma unroll
    for (int b = 0; b < 4; ++b)
        Vt[((size_t)(((b << 4) + h) << 6) + lane) * 2056 + 2048] = vn;
    // zero pad cols 2049..2055 of all 4096 rows
    int t = blockIdx.x * 256 + threadIdx.x;        // 0..1023
#pragma unroll
    for (int rr = 0; rr < 4; ++rr) {
        size_t row = (size_t)t * 4 + rr;
#pragma unroll
        for (int c = 0; c < 7; ++c)
            Vt[row * 2056 + 2049 + c] = 0;
    }
}

// ---------------- attention: BM=128 (4 waves x 32 rows), BT=64 tokens ------
// Logical token order = physical: positions 0..2047 real, 2048 null,
// 2049..2055 zero-pad (bias -512 kills them). K rows staged PERMUTED:
//   T(r) = 32*(r>>5) + 8*((r>>2)&3) + 4*((r>>4)&1) + (r&3)
// so exp(S^T) C-layout packs straight into PV's A-operand. V staged from
// VtG [bh][d][tok] via gl_lds with the K-style XOR-granule swizzle; each PV
// B-fragment is one conflict-free ds_read_b128. Tiles 0..31: staging =
// 4 pointer increments (strength-reduced); tile 32 special (null + clamp).
// Softmax denominator via ones-MFMA: rsacc[rg][r] lands on the lane that
// writes q-row quad*4+r -> no cross-lane reduction.
__global__ __launch_bounds__(256, 3) void attn_kernel(
    const unsigned short* __restrict__ qn,    // [B*2048,1024] l2norm*qs*log2e/8
    const unsigned short* __restrict__ kvK,   // [B*2048,1024] k bf16 (l2norm)
    const unsigned short* __restrict__ knull, // [16*64] bf16
    const unsigned short* __restrict__ Vt,    // [64bh][64d][2056tok] f16
    const int* __restrict__ mask,             // [B*2048]
    unsigned short* __restrict__ ao)          // [B*2048,1024]
{
    __shared__ __bf16    Kt[2][64 * 64];
    __shared__ _Float16  Vl[2][64 * 64];
    __shared__ __align__(16) float biasLds[2][64];

    const int tid = threadIdx.x, lane = tid & 63, wave = tid >> 6;
    const int quad = lane >> 4, l15 = lane & 15;
    const int bh = blockIdx.x;                 // (b,h): K/V sharers same XCD
    const int b = bh >> 4, h = bh & 15;
    const int mbase = blockIdx.y * 128 + wave * 32;
    const size_t rowoff = (size_t)b * 2048;

    bf16x8 qf[2][2];                           // B-operand fragments
#pragma unroll
    for (int rg = 0; rg < 2; ++rg)
#pragma unroll
        for (int ks = 0; ks < 2; ++ks)
            qf[rg][ks] = *(const bf16x8*)
                &qn[((rowoff + mbase + rg * 16 + l15) << 10) + (h << 6) + ks * 32 + quad * 8];

    const int t8  = lane >> 3;
    const int w7  = lane & 7;
    const int ksc = (w7 ^ t8) << 3;            // (r&7)==t8 since base%8==0
    const size_t vrow0 = ((size_t)bh << 6);    // first VtG row of this (b,h)

    const int r0v = wave * 16 + t8;            // LDS row (p=0) = V d-row
    const int r1v = wave * 16 + 8 + t8;        // LDS row (p=1)
    auto Tof = [](int r) {
        return ((r >> 5) << 5) | (((r >> 2) & 3) << 3)
             | (((r >> 4) & 1) << 2) | (r & 3);
    };
    const int T0 = Tof(r0v), T1 = Tof(r1v);    // T1 != 0 always

    // strength-reduced staging pointers (point at NEXT tile to issue)
    const unsigned short* kp0 = kvK + ((rowoff + T0) << 10) + (h << 6) + ksc;
    const unsigned short* kp1 = kvK + ((rowoff + T1) << 10) + (h << 6) + ksc;
    const unsigned short* vp0 = Vt + (vrow0 + r0v) * 2056 + ((w7 ^ t8) << 3);
    const unsigned short* vp1 = Vt + (vrow0 + r1v) * 2056 + ((w7 ^ t8) << 3);

    auto issueFast = [&](int bf) {
        gl_lds16(kp0, &Kt[bf][(wave * 16) * 64]);
        gl_lds16(kp1, &Kt[bf][(wave * 16 + 8) * 64]);
        gl_lds16(vp0, &Vl[bf][(wave * 16) * 64]);
        gl_lds16(vp1, &Vl[bf][(wave * 16 + 8) * 64]);
        kp0 += 65536; kp1 += 65536;            // 64 tokens * 1024 halfs
        vp0 += 64; vp1 += 64;                  // 8 granules
    };
    auto issue32 = [&](int bf) {               // tokens 2048..2111
        const unsigned short* kc =
            kvK + ((rowoff + 2047) << 10) + (h << 6) + ksc;   // finite clamp
        const unsigned short* s0 = (T0 == 0) ? knull + (h << 6) + ksc : kc;
        gl_lds16(s0, &Kt[bf][(wave * 16) * 64]);
        gl_lds16(kc, &Kt[bf][(wave * 16 + 8) * 64]);
        gl_lds16(Vt + (vrow0 + r0v) * 2056 + 2048, &Vl[bf][(wave * 16) * 64]);
        gl_lds16(Vt + (vrow0 + r1v) * 2056 + 2048, &Vl[bf][(wave * 16 + 8) * 64]);
    };
    auto biasFor = [&](int nt) -> float {      // wave 0 only
        int j = (nt << 6) + lane;
        float bv = -512.f;
        if (j < 2048) { if (mask[(b << 11) + j] != 0) bv = 0.f; }
        else if (j == 2048) bv = 0.f;
        return bv;
    };

    const uintv4 onesu = { 0x3c003c00u, 0x3c003c00u, 0x3c003c00u, 0x3c003c00u };
    const f16x8 ones = __builtin_bit_cast(f16x8, onesu);

    f32x4 O[2][4] = {};
    f32x4 rsacc[2] = {};

    issueFast(0);
    float bcur = 0.f;
    if (wave == 0) bcur = biasFor(0);

    for (int nt = 0; nt < 33; ++nt) {
        const int buf = nt & 1;
        if (wave == 0) biasLds[buf][lane] = bcur;
        __syncthreads();   // drains gl_lds(nt); bias(nt) visible; prev buf free
        if (nt < 31) {     // issue AFTER barrier: overlaps compute below
            issueFast(buf ^ 1);
            if (wave == 0) bcur = biasFor(nt + 1);
        } else if (nt == 31) {
            issue32(buf ^ 1);
            if (wave == 0) bcur = biasFor(32);
        }

#pragma unroll
        for (int g = 0; g < 2; ++g) {
            // --- QK^T: only one kf pair (8 VGPRs) live at a time ---
            float4 b0 = *(const float4*)&biasLds[buf][(g << 5) + (quad << 3)];
            float4 b1 = *(const float4*)&biasLds[buf][(g << 5) + (quad << 3) + 4];
            f32x4 s[2][2];
#pragma unroll
            for (int rg = 0; rg < 2; ++rg) {
                s[rg][0] = f32x4{ b0.x, b0.y, b0.z, b0.w };
                s[rg][1] = f32x4{ b1.x, b1.y, b1.z, b1.w };
            }
#pragma unroll
            for (int t = 0; t < 2; ++t) {
                const __bf16* kb = &Kt[buf][((g * 2 + t) * 16 + l15) * 64];
                bf16x8 k0 = *(const bf16x8*)&kb[(quad ^ (l15 & 7)) << 3];
                bf16x8 k1 = *(const bf16x8*)&kb[((4 + quad) ^ (l15 & 7)) << 3];
#pragma unroll
                for (int rg = 0; rg < 2; ++rg) {
                    s[rg][t] = mfma16(k0, qf[rg][0], s[rg][t]);
                    s[rg][t] = mfma16(k1, qf[rg][1], s[rg][t]);
                }
            }
            // --- V fragments: one b128 each, XOR-swizzled slot ---
            f16x8 vf8[4];
#pragma unroll
            for (int dt = 0; dt < 4; ++dt)
                vf8[dt] = *(const f16x8*)
                    &Vl[buf][(dt * 16 + l15) * 64
                             + ((((g << 2) + quad) ^ (l15 & 7)) << 3)];
            // --- exp2 + pack + PV (+ denominator via ones-MFMA) ---
#pragma unroll
            for (int rg = 0; rg < 2; ++rg) {
                float e0 = __builtin_amdgcn_exp2f(s[rg][0][0]);
                float e1 = __builtin_amdgcn_exp2f(s[rg][0][1]);
                float e2 = __builtin_amdgcn_exp2f(s[rg][0][2]);
                float e3 = __builtin_amdgcn_exp2f(s[rg][0][3]);
                float e4 = __builtin_amdgcn_exp2f(s[rg][1][0]);
                float e5 = __builtin_amdgcn_exp2f(s[rg][1][1]);
                float e6 = __builtin_amdgcn_exp2f(s[rg][1][2]);
                float e7 = __builtin_amdgcn_exp2f(s[rg][1][3]);
                uintv4 pu = { pk16(e0, e1), pk16(e2, e3),
                              pk16(e4, e5), pk16(e6, e7) };
                f16x8 p = __builtin_bit_cast(f16x8, pu);
                rsacc[rg] = mfma16h(p, ones, rsacc[rg]);
#pragma unroll
                for (int dt = 0; dt < 4; ++dt)
                    O[rg][dt] = mfma16h(p, vf8[dt], O[rg][dt]);
            }
        }
    }

    // rsacc[rg][r] = denom for q-row rg*16 + quad*4 + r (same lane as O rows)
#pragma unroll
    for (int rg = 0; rg < 2; ++rg) {
        float inv[4];
#pragma unroll
        for (int r = 0; r < 4; ++r) inv[r] = 1.f / rsacc[rg][r];
#pragma unroll
        for (int dt = 0; dt < 4; ++dt) {
            size_t base = ((rowoff + mbase + rg * 16 + quad * 4) << 10)
                        + (h << 6) + dt * 16 + l15;
#pragma unroll
            for (int r = 0; r < 4; ++r)
                ao[base + ((size_t)r << 10)] = f2b(O[rg][dt][r] * inv[r]);
        }
    }
}

// ---------------------------------------------------------------------------
extern "C" void kernel_launch(void* const* d_in, const int* in_sizes, int n_in,
                              void* d_out, int out_size, void* d_ws, size_t ws_size,
                              hipStream_t stream)
{
    const float* x       = (const float*)d_in[0];
    const int*   mask    = (const int*)d_in[1];
    const float* gamma   = (const float*)d_in[2];
    const float* null_kv = (const float*)d_in[3];
    const float* Wq      = (const float*)d_in[4];
    const float* Wkv     = (const float*)d_in[5];
    const float* q_scale = (const float*)d_in[6];
    const float* k_scale = (const float*)d_in[7];
    const float* Wout    = (const float*)d_in[8];

    // Workspace map (~70.07 MiB; ao aliases xn; WqT overlaps VtG tail --
    // WqT is dead after gemm<0>, before nullkv/gemm<1> write VtG):
    //   0        xn/ao   16 MiB
    //   16 MiB   q       16 MiB
    //   32 MiB   kvK     16 MiB   [tok][1024] bf16
    //   48 MiB   VtG     16.06 MiB = 4096 rows * 4112 B ([bh][d][2056] f16)
    //   VtGend-2MiB WqT  2 MiB    (inside VtG tail)
    //   VtGend   WkvT    4 MiB
    //   +4 MiB   WoutT   2 MiB
    //   +2 MiB   knull   2 KiB
    char* ws = (char*)d_ws;
    const size_t VTG_OFF  = (size_t)48u << 20;
    const size_t VTG_SIZE = (size_t)4096 * 4112;
    unsigned short* xn    = (unsigned short*)(ws);
    unsigned short* ao    = xn;                                    // reuse
    unsigned short* q     = (unsigned short*)(ws + ((size_t)16u << 20));
    unsigned short* kvK   = (unsigned short*)(ws + ((size_t)32u << 20));
    unsigned short* VtG   = (unsigned short*)(ws + VTG_OFF);
    unsigned short* WqT   = (unsigned short*)(ws + VTG_OFF + VTG_SIZE - ((size_t)2u << 20));
    unsigned short* WkvT  = (unsigned short*)(ws + VTG_OFF + VTG_SIZE);
    unsigned short* WoutT = (unsigned short*)(ws + VTG_OFF + VTG_SIZE + ((size_t)4u << 20));
    unsigned short* knull = (unsigned short*)(ws + VTG_OFF + VTG_SIZE + ((size_t)6u << 20));

    dim3 tb(32, 8);
    transpose_f2b<<<dim3(32, 32), tb, 0, stream>>>(Wq,   WqT,   1024, 1024);
    transpose_f2b<<<dim3(64, 32), tb, 0, stream>>>(Wkv,  WkvT,  1024, 2048);
    transpose_f2b<<<dim3(32, 32), tb, 0, stream>>>(Wout, WoutT, 1024, 1024);

    ln_kernel<<<8192, 256, 0, stream>>>(x, gamma, xn);

    gemm_bt<0><<<dim3(8, 64),  256, 0, stream>>>(xn, WqT, q, q_scale, nullptr,
                                                 8192, 1024, 1024, 1024);
    // nullkv after gemm<0> (WqT dead); writes VtG col 2048 + zero pad
    nullkv_kernel<<<4, 256, 0, stream>>>(null_kv, k_scale, knull, VtG);

    gemm_bt<1><<<dim3(16, 64), 256, 0, stream>>>(xn, WkvT, kvK, k_scale, VtG,
                                                 8192, 2048, 1024, 1024);

    attn_kernel<<<dim3(64, 16), 256, 0, stream>>>(q, kvK, knull, VtG, mask, ao);

    gemm_bt<2><<<dim3(8, 64), 256, 0, stream>>>(ao, WoutT, d_out, nullptr, nullptr,
                                                8192, 1024, 1024, 1024);
}

// Round 4
// 298.814 us; speedup vs baseline: 1.0212x; 1.0212x over previous
//
#include <hip/hip_runtime.h>
#include <hip/hip_bf16.h>
#include <stdint.h>

// ---------------------------------------------------------------------------
// fp32 inputs; mask int32; fp32 output. Internal pipeline bf16/f16.
// LayerNorm -> fused {q,kv} proj GEMMs with l2norm epilogues (V emitted f16
//   TRANSPOSED [b,h][d][token], null token at column 2048, zero pad 2049..55)
//   -> flash attn: S^T = K.Q^T (16x16x32 bf16) with PERMUTED K-token rows so
//      exp(S^T) packs straight into the A-operand of 16x16x32 f16 PV MFMAs;
//      mask applied as 0/-512 bias in the QK C-initializer -> out proj.
// R13: (a) GEMM reverted to the R11 single-buffer 2-barrier m97 structure —
//      R12's explicit dbuf was a measured regression (+8us; Common-mistake #5:
//      compiler's vmcnt(0)-before-barrier drain is structural, and dbuf LDS
//      cost gemm<1> a resident block: 48->64KB = 3->2 blocks/CU).
//      (b) attn __launch_bounds__ (256,3)->(256,4): R11's register diet left
//      attn at 64 VGPR (<128 budget, no spill risk; R9's 84-VGPR objection is
//      obsolete) and LDS 33280*4=133KB<160KB. Grid is exactly 4 blocks/CU of
//      work; residency 3 forced a 256-block straggler tail at 1/3 occupancy
//      (OccupancyPercent 32%). Now: one full resident pass, 4 waves/SIMD.
// ---------------------------------------------------------------------------

using f32x4  = __attribute__((ext_vector_type(4))) float;
using bf16x8 = __attribute__((ext_vector_type(8))) __bf16;
using f16x8  = __attribute__((ext_vector_type(8))) _Float16;
using uintv4 = __attribute__((ext_vector_type(4))) unsigned int;

__device__ __forceinline__ float b2f(unsigned short u) {
    return __uint_as_float(((unsigned)u) << 16);
}
__device__ __forceinline__ unsigned short f2b(float f) {
    unsigned u = __float_as_uint(f);
    u += 0x7fffu + ((u >> 16) & 1u);   // RNE
    return (unsigned short)(u >> 16);
}
__device__ __forceinline__ unsigned short f2h(float f) {   // RNE f32->f16
    return __builtin_bit_cast(unsigned short, (_Float16)f);
}
__device__ __forceinline__ f32x4 mfma16(bf16x8 a, bf16x8 b, f32x4 c) {
    return __builtin_amdgcn_mfma_f32_16x16x32_bf16(a, b, c, 0, 0, 0);
}
__device__ __forceinline__ f32x4 mfma16h(f16x8 a, f16x8 b, f32x4 c) {
    return __builtin_amdgcn_mfma_f32_16x16x32_f16(a, b, c, 0, 0, 0);
}
// packed f32x2 -> f16x2 (RTZ), returned as the raw 32-bit pattern
__device__ __forceinline__ unsigned pk16(float a, float b) {
    return __builtin_bit_cast(unsigned, __builtin_amdgcn_cvt_pkrtz(a, b));
}
// async global->LDS, 16B/lane; LDS dst = wave-uniform base + lane*16
__device__ __forceinline__ void gl_lds16(const void* g, void* l) {
    __builtin_amdgcn_global_load_lds(
        (const __attribute__((address_space(1))) unsigned int*)g,
        (__attribute__((address_space(3))) unsigned int*)l, 16, 0, 0);
}

// ------------- weight transpose + fp32->bf16: in[R][C] -> out[C][R] --------
__global__ __launch_bounds__(256) void transpose_f2b(
    const float* __restrict__ in, unsigned short* __restrict__ out,
    int R, int C)
{
    __shared__ unsigned short t[32][33];
    int tx = threadIdx.x, ty = threadIdx.y;       // (32,8)
    int c = blockIdx.x * 32 + tx;
#pragma unroll
    for (int i = 0; i < 4; ++i) {
        int r = blockIdx.y * 32 + ty + i * 8;
        t[ty + i * 8][tx] = f2b(in[(size_t)r * C + c]);
    }
    __syncthreads();
    int r2 = blockIdx.y * 32 + tx;
#pragma unroll
    for (int i = 0; i < 4; ++i) {
        int c2 = blockIdx.x * 32 + ty + i * 8;
        out[(size_t)c2 * R + r2] = t[tx][ty + i * 8];
    }
}

// -------- LayerNorm: one row (1024 fp32) per block of 256 -> bf16 ----------
__global__ __launch_bounds__(256) void ln_kernel(
    const float* __restrict__ x, const float* __restrict__ gamma,
    unsigned short* __restrict__ xn)
{
    int row = blockIdx.x, tid = threadIdx.x;
    int wave = tid >> 6, lane = tid & 63;
    float4 raw = *(const float4*)(x + ((size_t)row << 10) + (tid << 2));
    float v[4] = { raw.x, raw.y, raw.z, raw.w };
    float s  = v[0] + v[1] + v[2] + v[3];
    float s2 = v[0]*v[0] + v[1]*v[1] + v[2]*v[2] + v[3]*v[3];
#pragma unroll
    for (int off = 1; off < 64; off <<= 1) {
        s  += __shfl_xor(s, off);
        s2 += __shfl_xor(s2, off);
    }
    __shared__ float ps[4], ps2[4], sh[2];
    if (lane == 0) { ps[wave] = s; ps2[wave] = s2; }
    __syncthreads();
    if (tid == 0) {
        float S  = ps[0] + ps[1] + ps[2] + ps[3];
        float S2 = ps2[0] + ps2[1] + ps2[2] + ps2[3];
        float mu  = S * (1.f / 1024.f);
        float var = S2 * (1.f / 1024.f) - mu * mu;
        sh[0] = mu; sh[1] = rsqrtf(var + 1e-5f);
    }
    __syncthreads();
    float mu = sh[0], rstd = sh[1];
    float4 g4 = *(const float4*)(gamma + (tid << 2));
    float g[4] = { g4.x, g4.y, g4.z, g4.w };
    unsigned short o[4];
#pragma unroll
    for (int i = 0; i < 4; ++i) o[i] = f2b((v[i] - mu) * rstd * g[i]);
    uint2 out;
    out.x = (unsigned)o[0] | ((unsigned)o[1] << 16);
    out.y = (unsigned)o[2] | ((unsigned)o[3] << 16);
    *(uint2*)(xn + ((size_t)row << 10) + (tid << 2)) = out;
}

// ---- GEMM C[M,N]=A[M,K]*Bt[N,K]^T, 128x128, gl_lds staging, fused epilog --
// m97 structure: stage -> sync -> compute -> sync (R12's dbuf regressed).
// MODE 0 (QNORM): per-head l2norm rows + q_scale*0.125*log2e, bf16 out
// MODE 1 (KV):    cols<1024: l2norm + k_scale, bf16 -> Cout (ldc=1024);
//                 cols>=1024: raw f16 TRANSPOSED -> Vout[b*16+h][d][tok]
//                 (row stride 2056 halfs) via per-wave LDS transpose,
//                 contiguous uint2 stores.
// MODE 2 (F32):   plain f32 store
template<int MODE>
__global__ __launch_bounds__(256, 2) void gemm_bt(
    const unsigned short* __restrict__ A, const unsigned short* __restrict__ Bt,
    void* __restrict__ Cout, const float* __restrict__ scale,
    unsigned short* __restrict__ Vout,
    int M, int N, int K, int ldc)
{
    __shared__ __bf16 As[128 * 32];
    __shared__ __bf16 Bs[128 * 32];
    int tid = threadIdx.x, lane = tid & 63, wave = tid >> 6;
    int quad = lane >> 4, l15 = lane & 15;
    int m0 = blockIdx.y * 128, n0 = blockIdx.x * 128;
    int wm = (wave & 1) * 64, wn = (wave >> 1) * 64;
    f32x4 acc[4][4] = {};

    const int srow = wave * 32 + (lane >> 2);
    const int scol = (lane & 3) << 3;
    const unsigned short* gA = A  + (size_t)(m0 + srow) * K + scol;
    const unsigned short* gB = Bt + (size_t)(n0 + srow) * K + scol;
    __bf16* lA0 = &As[(wave * 32) * 32];
    __bf16* lA1 = &As[(wave * 32 + 16) * 32];
    __bf16* lB0 = &Bs[(wave * 32) * 32];
    __bf16* lB1 = &Bs[(wave * 32 + 16) * 32];
    const size_t rstep = (size_t)16 * K;

    for (int k0 = 0; k0 < K; k0 += 32) {
        gl_lds16(gA,         lA0);
        gl_lds16(gA + rstep, lA1);
        gl_lds16(gB,         lB0);
        gl_lds16(gB + rstep, lB1);
        gA += 32; gB += 32;
        __syncthreads();
        bf16x8 af[4], bfv[4];
#pragma unroll
        for (int i = 0; i < 4; ++i)
            af[i] = *(const bf16x8*)&As[(wm + i * 16 + l15) * 32 + quad * 8];
#pragma unroll
        for (int j = 0; j < 4; ++j)
            bfv[j] = *(const bf16x8*)&Bs[(wn + j * 16 + l15) * 32 + quad * 8];
#pragma unroll
        for (int i = 0; i < 4; ++i)
#pragma unroll
            for (int j = 0; j < 4; ++j)
                acc[i][j] = mfma16(af[i], bfv[j], acc[i][j]);
        __syncthreads();
    }

    if (MODE == 2) {
#pragma unroll
        for (int i = 0; i < 4; ++i)
#pragma unroll
            for (int j = 0; j < 4; ++j) {
                int row = m0 + wm + i * 16 + quad * 4;
                int col = n0 + wn + j * 16 + l15;
                size_t base = (size_t)row * ldc + col;
#pragma unroll
                for (int r = 0; r < 4; ++r)
                    ((float*)Cout)[base + (size_t)r * ldc] = acc[i][j][r];
            }
        return;
    }

    // wave's 64 cols (wn + j*16 + l15) = exactly one head; head-dim = j*16+l15
    if constexpr (MODE == 1) {
        const bool isv = (n0 + wn) >= 1024;
        if (isv) {
            // per-wave 64x64 (tok x d) tile -> LDS transposed with XOR
            // swizzle tok^((d&7)<<3) -> contiguous uint2 global stores.
            __shared__ unsigned short Vx[4][64 * 64];   // 32 KB (MODE 1 only)
            unsigned short* tileL = Vx[wave];
            int hv = (n0 + wn - 1024) >> 6;
            int bidx = m0 >> 11;                        // block never straddles
            int tok0w = (m0 + wm) & 2047;
            size_t vbase = (size_t)((((bidx << 4) + hv) << 6)) * 2056;
#pragma unroll
            for (int i = 0; i < 4; ++i)
#pragma unroll
                for (int j = 0; j < 4; ++j) {
                    int d = j * 16 + l15;
                    int tk = (i * 16 + quad * 4) ^ ((d & 7) << 3);
                    unsigned u01 = (unsigned)f2h(acc[i][j][0])
                                 | ((unsigned)f2h(acc[i][j][1]) << 16);
                    unsigned u23 = (unsigned)f2h(acc[i][j][2])
                                 | ((unsigned)f2h(acc[i][j][3]) << 16);
                    *(unsigned*)&tileL[d * 64 + tk]     = u01;
                    *(unsigned*)&tileL[d * 64 + tk + 2] = u23;
                }
            // same-wave read-out (compiler orders via lgkmcnt)
#pragma unroll
            for (int rr = 0; rr < 16; ++rr) {
                int d = rr * 4 + quad;
                uint2 val = *(const uint2*)
                    &tileL[d * 64 + ((l15 * 4) ^ ((d & 7) << 3))];
                *(uint2*)(Vout + vbase + (size_t)d * 2056 + tok0w + l15 * 4) = val;
            }
            return;
        }
    }

    float sc[4];
#pragma unroll
    for (int j = 0; j < 4; ++j) {
        float s = scale[j * 16 + l15];
        sc[j] = (MODE == 0) ? s * (0.125f * 1.44269504088896f) : s;
    }
#pragma unroll
    for (int i = 0; i < 4; ++i)
#pragma unroll
        for (int r = 0; r < 4; ++r) {
            float ss = 0.f;
#pragma unroll
            for (int j = 0; j < 4; ++j) ss += acc[i][j][r] * acc[i][j][r];
            ss += __shfl_xor(ss, 1); ss += __shfl_xor(ss, 2);
            ss += __shfl_xor(ss, 4); ss += __shfl_xor(ss, 8);
            float mul = rsqrtf(ss + 1e-12f);
            size_t rowbase = (size_t)(m0 + wm + i * 16 + quad * 4 + r) * ldc
                           + n0 + wn + l15;
#pragma unroll
            for (int j = 0; j < 4; ++j) {
                float v = acc[i][j][r];
                ((unsigned short*)Cout)[rowbase + j * 16] = f2b(v * mul * sc[j]);
            }
        }
}

// -- null kv: l2norm k + k_scale (bf16); v -> VtG col 2048; zero 2049..2055 -
// Runs AFTER gemm<0> (WqT, overlapped into VtG tail, is dead by then).
__global__ __launch_bounds__(256) void nullkv_kernel(
    const float* __restrict__ null_kv, const float* __restrict__ k_scale,
    unsigned short* __restrict__ knull, unsigned short* __restrict__ Vt)
{
    int wave = threadIdx.x >> 6, lane = threadIdx.x & 63;
    int h = blockIdx.x * 4 + wave;
    int idx = (h << 6) + lane;
    float kvl = null_kv[idx];
    float ss = kvl * kvl;
#pragma unroll
    for (int off = 1; off < 64; off <<= 1) ss += __shfl_xor(ss, off);
    knull[idx] = f2b(kvl * rsqrtf(ss + 1e-12f) * k_scale[lane]);
    unsigned short vn = f2h(null_kv[1024 + idx]);
#pragma unroll
    for (int b = 0; b < 4; ++b)
        Vt[((size_t)(((b << 4) + h) << 6) + lane) * 2056 + 2048] = vn;
    // zero pad cols 2049..2055 of all 4096 rows
    int t = blockIdx.x * 256 + threadIdx.x;        // 0..1023
#pragma unroll
    for (int rr = 0; rr < 4; ++rr) {
        size_t row = (size_t)t * 4 + rr;
#pragma unroll
        for (int c = 0; c < 7; ++c)
            Vt[row * 2056 + 2049 + c] = 0;
    }
}

// ---------------- attention: BM=128 (4 waves x 32 rows), BT=64 tokens ------
// Logical token order = physical: positions 0..2047 real, 2048 null,
// 2049..2055 zero-pad (bias -512 kills them). K rows staged PERMUTED:
//   T(r) = 32*(r>>5) + 8*((r>>2)&3) + 4*((r>>4)&1) + (r&3)
// so exp(S^T) C-layout packs straight into PV's A-operand. V staged from
// VtG [bh][d][tok] via gl_lds with the K-style XOR-granule swizzle; each PV
// B-fragment is one conflict-free ds_read_b128. Tiles 0..31: staging =
// 4 pointer increments (strength-reduced); tile 32 special (null + clamp).
// Softmax denominator via ones-MFMA: rsacc[rg][r] lands on the lane that
// writes q-row quad*4+r -> no cross-lane reduction.
// launch_bounds (256,4): 64 VGPR fits the 128 budget; grid = exactly
// 4 blocks/CU -> one full resident pass (was 3 resident + straggler tail).
__global__ __launch_bounds__(256, 4) void attn_kernel(
    const unsigned short* __restrict__ qn,    // [B*2048,1024] l2norm*qs*log2e/8
    const unsigned short* __restrict__ kvK,   // [B*2048,1024] k bf16 (l2norm)
    const unsigned short* __restrict__ knull, // [16*64] bf16
    const unsigned short* __restrict__ Vt,    // [64bh][64d][2056tok] f16
    const int* __restrict__ mask,             // [B*2048]
    unsigned short* __restrict__ ao)          // [B*2048,1024]
{
    __shared__ __bf16    Kt[2][64 * 64];
    __shared__ _Float16  Vl[2][64 * 64];
    __shared__ __align__(16) float biasLds[2][64];

    const int tid = threadIdx.x, lane = tid & 63, wave = tid >> 6;
    const int quad = lane >> 4, l15 = lane & 15;
    const int bh = blockIdx.x;                 // (b,h): K/V sharers same XCD
    const int b = bh >> 4, h = bh & 15;
    const int mbase = blockIdx.y * 128 + wave * 32;
    const size_t rowoff = (size_t)b * 2048;

    bf16x8 qf[2][2];                           // B-operand fragments
#pragma unroll
    for (int rg = 0; rg < 2; ++rg)
#pragma unroll
        for (int ks = 0; ks < 2; ++ks)
            qf[rg][ks] = *(const bf16x8*)
                &qn[((rowoff + mbase + rg * 16 + l15) << 10) + (h << 6) + ks * 32 + quad * 8];

    const int t8  = lane >> 3;
    const int w7  = lane & 7;
    const int ksc = (w7 ^ t8) << 3;            // (r&7)==t8 since base%8==0
    const size_t vrow0 = ((size_t)bh << 6);    // first VtG row of this (b,h)

    const int r0v = wave * 16 + t8;            // LDS row (p=0) = V d-row
    const int r1v = wave * 16 + 8 + t8;        // LDS row (p=1)
    auto Tof = [](int r) {
        return ((r >> 5) << 5) | (((r >> 2) & 3) << 3)
             | (((r >> 4) & 1) << 2) | (r & 3);
    };
    const int T0 = Tof(r0v), T1 = Tof(r1v);    // T1 != 0 always

    // strength-reduced staging pointers (point at NEXT tile to issue)
    const unsigned short* kp0 = kvK + ((rowoff + T0) << 10) + (h << 6) + ksc;
    const unsigned short* kp1 = kvK + ((rowoff + T1) << 10) + (h << 6) + ksc;
    const unsigned short* vp0 = Vt + (vrow0 + r0v) * 2056 + ((w7 ^ t8) << 3);
    const unsigned short* vp1 = Vt + (vrow0 + r1v) * 2056 + ((w7 ^ t8) << 3);

    auto issueFast = [&](int bf) {
        gl_lds16(kp0, &Kt[bf][(wave * 16) * 64]);
        gl_lds16(kp1, &Kt[bf][(wave * 16 + 8) * 64]);
        gl_lds16(vp0, &Vl[bf][(wave * 16) * 64]);
        gl_lds16(vp1, &Vl[bf][(wave * 16 + 8) * 64]);
        kp0 += 65536; kp1 += 65536;            // 64 tokens * 1024 halfs
        vp0 += 64; vp1 += 64;                  // 8 granules
    };
    auto issue32 = [&](int bf) {               // tokens 2048..2111
        const unsigned short* kc =
            kvK + ((rowoff + 2047) << 10) + (h << 6) + ksc;   // finite clamp
        const unsigned short* s0 = (T0 == 0) ? knull + (h << 6) + ksc : kc;
        gl_lds16(s0, &Kt[bf][(wave * 16) * 64]);
        gl_lds16(kc, &Kt[bf][(wave * 16 + 8) * 64]);
        gl_lds16(Vt + (vrow0 + r0v) * 2056 + 2048, &Vl[bf][(wave * 16) * 64]);
        gl_lds16(Vt + (vrow0 + r1v) * 2056 + 2048, &Vl[bf][(wave * 16 + 8) * 64]);
    };
    auto biasFor = [&](int nt) -> float {      // wave 0 only
        int j = (nt << 6) + lane;
        float bv = -512.f;
        if (j < 2048) { if (mask[(b << 11) + j] != 0) bv = 0.f; }
        else if (j == 2048) bv = 0.f;
        return bv;
    };

    const uintv4 onesu = { 0x3c003c00u, 0x3c003c00u, 0x3c003c00u, 0x3c003c00u };
    const f16x8 ones = __builtin_bit_cast(f16x8, onesu);

    f32x4 O[2][4] = {};
    f32x4 rsacc[2] = {};

    issueFast(0);
    float bcur = 0.f;
    if (wave == 0) bcur = biasFor(0);

    for (int nt = 0; nt < 33; ++nt) {
        const int buf = nt & 1;
        if (wave == 0) biasLds[buf][lane] = bcur;
        __syncthreads();   // drains gl_lds(nt); bias(nt) visible; prev buf free
        if (nt < 31) {     // issue AFTER barrier: overlaps compute below
            issueFast(buf ^ 1);
            if (wave == 0) bcur = biasFor(nt + 1);
        } else if (nt == 31) {
            issue32(buf ^ 1);
            if (wave == 0) bcur = biasFor(32);
        }

#pragma unroll
        for (int g = 0; g < 2; ++g) {
            // --- QK^T: only one kf pair (8 VGPRs) live at a time ---
            float4 b0 = *(const float4*)&biasLds[buf][(g << 5) + (quad << 3)];
            float4 b1 = *(const float4*)&biasLds[buf][(g << 5) + (quad << 3) + 4];
            f32x4 s[2][2];
#pragma unroll
            for (int rg = 0; rg < 2; ++rg) {
                s[rg][0] = f32x4{ b0.x, b0.y, b0.z, b0.w };
                s[rg][1] = f32x4{ b1.x, b1.y, b1.z, b1.w };
            }
#pragma unroll
            for (int t = 0; t < 2; ++t) {
                const __bf16* kb = &Kt[buf][((g * 2 + t) * 16 + l15) * 64];
                bf16x8 k0 = *(const bf16x8*)&kb[(quad ^ (l15 & 7)) << 3];
                bf16x8 k1 = *(const bf16x8*)&kb[((4 + quad) ^ (l15 & 7)) << 3];
#pragma unroll
                for (int rg = 0; rg < 2; ++rg) {
                    s[rg][t] = mfma16(k0, qf[rg][0], s[rg][t]);
                    s[rg][t] = mfma16(k1, qf[rg][1], s[rg][t]);
                }
            }
            // --- V fragments: one b128 each, XOR-swizzled slot ---
            f16x8 vf8[4];
#pragma unroll
            for (int dt = 0; dt < 4; ++dt)
                vf8[dt] = *(const f16x8*)
                    &Vl[buf][(dt * 16 + l15) * 64
                             + ((((g << 2) + quad) ^ (l15 & 7)) << 3)];
            // --- exp2 + pack + PV (+ denominator via ones-MFMA) ---
#pragma unroll
            for (int rg = 0; rg < 2; ++rg) {
                float e0 = __builtin_amdgcn_exp2f(s[rg][0][0]);
                float e1 = __builtin_amdgcn_exp2f(s[rg][0][1]);
                float e2 = __builtin_amdgcn_exp2f(s[rg][0][2]);
                float e3 = __builtin_amdgcn_exp2f(s[rg][0][3]);
                float e4 = __builtin_amdgcn_exp2f(s[rg][1][0]);
                float e5 = __builtin_amdgcn_exp2f(s[rg][1][1]);
                float e6 = __builtin_amdgcn_exp2f(s[rg][1][2]);
                float e7 = __builtin_amdgcn_exp2f(s[rg][1][3]);
                uintv4 pu = { pk16(e0, e1), pk16(e2, e3),
                              pk16(e4, e5), pk16(e6, e7) };
                f16x8 p = __builtin_bit_cast(f16x8, pu);
                rsacc[rg] = mfma16h(p, ones, rsacc[rg]);
#pragma unroll
                for (int dt = 0; dt < 4; ++dt)
                    O[rg][dt] = mfma16h(p, vf8[dt], O[rg][dt]);
            }
        }
    }

    // rsacc[rg][r] = denom for q-row rg*16 + quad*4 + r (same lane as O rows)
#pragma unroll
    for (int rg = 0; rg < 2; ++rg) {
        float inv[4];
#pragma unroll
        for (int r = 0; r < 4; ++r) inv[r] = 1.f / rsacc[rg][r];
#pragma unroll
        for (int dt = 0; dt < 4; ++dt) {
            size_t base = ((rowoff + mbase + rg * 16 + quad * 4) << 10)
                        + (h << 6) + dt * 16 + l15;
#pragma unroll
            for (int r = 0; r < 4; ++r)
                ao[base + ((size_t)r << 10)] = f2b(O[rg][dt][r] * inv[r]);
        }
    }
}

// ---------------------------------------------------------------------------
extern "C" void kernel_launch(void* const* d_in, const int* in_sizes, int n_in,
                              void* d_out, int out_size, void* d_ws, size_t ws_size,
                              hipStream_t stream)
{
    const float* x       = (const float*)d_in[0];
    const int*   mask    = (const int*)d_in[1];
    const float* gamma   = (const float*)d_in[2];
    const float* null_kv = (const float*)d_in[3];
    const float* Wq      = (const float*)d_in[4];
    const float* Wkv     = (const float*)d_in[5];
    const float* q_scale = (const float*)d_in[6];
    const float* k_scale = (const float*)d_in[7];
    const float* Wout    = (const float*)d_in[8];

    // Workspace map (~70.07 MiB; ao aliases xn; WqT overlaps VtG tail --
    // WqT is dead after gemm<0>, before nullkv/gemm<1> write VtG):
    //   0        xn/ao   16 MiB
    //   16 MiB   q       16 MiB
    //   32 MiB   kvK     16 MiB   [tok][1024] bf16
    //   48 MiB   VtG     16.06 MiB = 4096 rows * 4112 B ([bh][d][2056] f16)
    //   VtGend-2MiB WqT  2 MiB    (inside VtG tail)
    //   VtGend   WkvT    4 MiB
    //   +4 MiB   WoutT   2 MiB
    //   +2 MiB   knull   2 KiB
    char* ws = (char*)d_ws;
    const size_t VTG_OFF  = (size_t)48u << 20;
    const size_t VTG_SIZE = (size_t)4096 * 4112;
    unsigned short* xn    = (unsigned short*)(ws);
    unsigned short* ao    = xn;                                    // reuse
    unsigned short* q     = (unsigned short*)(ws + ((size_t)16u << 20));
    unsigned short* kvK   = (unsigned short*)(ws + ((size_t)32u << 20));
    unsigned short* VtG   = (unsigned short*)(ws + VTG_OFF);
    unsigned short* WqT   = (unsigned short*)(ws + VTG_OFF + VTG_SIZE - ((size_t)2u << 20));
    unsigned short* WkvT  = (unsigned short*)(ws + VTG_OFF + VTG_SIZE);
    unsigned short* WoutT = (unsigned short*)(ws + VTG_OFF + VTG_SIZE + ((size_t)4u << 20));
    unsigned short* knull = (unsigned short*)(ws + VTG_OFF + VTG_SIZE + ((size_t)6u << 20));

    dim3 tb(32, 8);
    transpose_f2b<<<dim3(32, 32), tb, 0, stream>>>(Wq,   WqT,   1024, 1024);
    transpose_f2b<<<dim3(64, 32), tb, 0, stream>>>(Wkv,  WkvT,  1024, 2048);
    transpose_f2b<<<dim3(32, 32), tb, 0, stream>>>(Wout, WoutT, 1024, 1024);

    ln_kernel<<<8192, 256, 0, stream>>>(x, gamma, xn);

    gemm_bt<0><<<dim3(8, 64),  256, 0, stream>>>(xn, WqT, q, q_scale, nullptr,
                                                 8192, 1024, 1024, 1024);
    // nullkv after gemm<0> (WqT dead); writes VtG col 2048 + zero pad
    nullkv_kernel<<<4, 256, 0, stream>>>(null_kv, k_scale, knull, VtG);

    gemm_bt<1><<<dim3(16, 64), 256, 0, stream>>>(xn, WkvT, kvK, k_scale, VtG,
                                                 8192, 2048, 1024, 1024);

    attn_kernel<<<dim3(64, 16), 256, 0, stream>>>(q, kvK, knull, VtG, mask, ao);

    gemm_bt<2><<<dim3(8, 64), 256, 0, stream>>>(ao, WoutT, d_out, nullptr, nullptr,
                                                8192, 1024, 1024, 1024);
}

// Round 5
// 289.504 us; speedup vs baseline: 1.0541x; 1.0322x over previous
//
#include <hip/hip_runtime.h>
#include <hip/hip_bf16.h>
#include <stdint.h>

// ---------------------------------------------------------------------------
// fp32 inputs; mask int32; fp32 output. Internal pipeline bf16/f16.
// LayerNorm -> ONE fused QKV GEMM (Wq|Wkv concatenated) with l2norm epilogues
//   (V emitted f16 TRANSPOSED [b,h][d][token], null token at col 2048)
//   -> flash attn (R11 structure, unchanged) -> out proj GEMM.
// R14: GEMM rebuilt inside the verified 2-barrier structure:
//   (a) BK=64 (halves the 64 vmcnt(0) barrier drains per block to 32;
//       2x MFMA per drain).
//   (b) T2 XOR-granule swizzle on the LDS tiles via PRE-SWIZZLED global
//       source (same (w7^row8) pattern as attn's K staging): the old
//       As[row*32+quad*8] ds_read_b128 was ~8-way bank-conflicted (lanes
//       0..15 hit 2 bank-groups); now <=2-way (free).
//   (c) gemm<0>+gemm<1> fused into one QKV dispatch over WqkvT[3072][1024],
//       per-block epilogue mode by blockIdx.x (Q / K-l2norm / V-transpose).
//       V-transpose LDS tile aliases the staging LDS (dead after K-loop).
//   (d) workspace repack: WqkvT after VtG (6 MiB); WoutT lives in the dead
//       q buffer, written by a transpose launched after attn.
//   attn/LN/transpose/nullkv code unchanged from R13.
// ---------------------------------------------------------------------------

using f32x4  = __attribute__((ext_vector_type(4))) float;
using bf16x8 = __attribute__((ext_vector_type(8))) __bf16;
using f16x8  = __attribute__((ext_vector_type(8))) _Float16;
using uintv4 = __attribute__((ext_vector_type(4))) unsigned int;

__device__ __forceinline__ unsigned short f2b(float f) {
    unsigned u = __float_as_uint(f);
    u += 0x7fffu + ((u >> 16) & 1u);   // RNE
    return (unsigned short)(u >> 16);
}
__device__ __forceinline__ unsigned short f2h(float f) {   // RNE f32->f16
    return __builtin_bit_cast(unsigned short, (_Float16)f);
}
__device__ __forceinline__ f32x4 mfma16(bf16x8 a, bf16x8 b, f32x4 c) {
    return __builtin_amdgcn_mfma_f32_16x16x32_bf16(a, b, c, 0, 0, 0);
}
__device__ __forceinline__ f32x4 mfma16h(f16x8 a, f16x8 b, f32x4 c) {
    return __builtin_amdgcn_mfma_f32_16x16x32_f16(a, b, c, 0, 0, 0);
}
// packed f32x2 -> f16x2 (RTZ), returned as the raw 32-bit pattern
__device__ __forceinline__ unsigned pk16(float a, float b) {
    return __builtin_bit_cast(unsigned, __builtin_amdgcn_cvt_pkrtz(a, b));
}
// async global->LDS, 16B/lane; LDS dst = wave-uniform base + lane*16
__device__ __forceinline__ void gl_lds16(const void* g, void* l) {
    __builtin_amdgcn_global_load_lds(
        (const __attribute__((address_space(1))) unsigned int*)g,
        (__attribute__((address_space(3))) unsigned int*)l, 16, 0, 0);
}

// ------------- weight transpose + fp32->bf16: in[R][C] -> out[C][R] --------
__global__ __launch_bounds__(256) void transpose_f2b(
    const float* __restrict__ in, unsigned short* __restrict__ out,
    int R, int C)
{
    __shared__ unsigned short t[32][33];
    int tx = threadIdx.x, ty = threadIdx.y;       // (32,8)
    int c = blockIdx.x * 32 + tx;
#pragma unroll
    for (int i = 0; i < 4; ++i) {
        int r = blockIdx.y * 32 + ty + i * 8;
        t[ty + i * 8][tx] = f2b(in[(size_t)r * C + c]);
    }
    __syncthreads();
    int r2 = blockIdx.y * 32 + tx;
#pragma unroll
    for (int i = 0; i < 4; ++i) {
        int c2 = blockIdx.x * 32 + ty + i * 8;
        out[(size_t)c2 * R + r2] = t[tx][ty + i * 8];
    }
}

// -------- LayerNorm: one row (1024 fp32) per block of 256 -> bf16 ----------
__global__ __launch_bounds__(256) void ln_kernel(
    const float* __restrict__ x, const float* __restrict__ gamma,
    unsigned short* __restrict__ xn)
{
    int row = blockIdx.x, tid = threadIdx.x;
    int wave = tid >> 6, lane = tid & 63;
    float4 raw = *(const float4*)(x + ((size_t)row << 10) + (tid << 2));
    float v[4] = { raw.x, raw.y, raw.z, raw.w };
    float s  = v[0] + v[1] + v[2] + v[3];
    float s2 = v[0]*v[0] + v[1]*v[1] + v[2]*v[2] + v[3]*v[3];
#pragma unroll
    for (int off = 1; off < 64; off <<= 1) {
        s  += __shfl_xor(s, off);
        s2 += __shfl_xor(s2, off);
    }
    __shared__ float ps[4], ps2[4], sh[2];
    if (lane == 0) { ps[wave] = s; ps2[wave] = s2; }
    __syncthreads();
    if (tid == 0) {
        float S  = ps[0] + ps[1] + ps[2] + ps[3];
        float S2 = ps2[0] + ps2[1] + ps2[2] + ps2[3];
        float mu  = S * (1.f / 1024.f);
        float var = S2 * (1.f / 1024.f) - mu * mu;
        sh[0] = mu; sh[1] = rsqrtf(var + 1e-5f);
    }
    __syncthreads();
    float mu = sh[0], rstd = sh[1];
    float4 g4 = *(const float4*)(gamma + (tid << 2));
    float g[4] = { g4.x, g4.y, g4.z, g4.w };
    unsigned short o[4];
#pragma unroll
    for (int i = 0; i < 4; ++i) o[i] = f2b((v[i] - mu) * rstd * g[i]);
    uint2 out;
    out.x = (unsigned)o[0] | ((unsigned)o[1] << 16);
    out.y = (unsigned)o[2] | ((unsigned)o[3] << 16);
    *(uint2*)(xn + ((size_t)row << 10) + (tid << 2)) = out;
}

// ---- GEMM C=A[8192,K]*Bt[N,K]^T, 128x128 tile, BK=64, swizzled LDS -------
// 2-barrier m97 structure (R12's dbuf regressed; kept). LDS tiles are
// [row][64] with granule g at slot g^(row&7): staged via pre-swizzled
// global source (gl_lds dest stays linear), read back with the same XOR ->
// ds_read_b128 <=2-way bank conflict (was ~8-way at BK=32 linear).
// MODE 0 (fused QKV): bx<8: Q l2norm*q_scale*0.125*log2e -> C0 (bf16,ldc1024)
//                     bx 8..15: K l2norm*k_scale -> Ck (bf16, ldc 1024)
//                     bx>=16: V raw f16 transposed -> Vout[b*16+h][d][tok]
//                             (LDS transpose tile aliases staging smem)
// MODE 2: plain f32 store -> C0 (ldc 1024)
template<int MODE>
__global__ __launch_bounds__(256, 2) void gemm_bt(
    const unsigned short* __restrict__ A,
    const unsigned short* __restrict__ Bt,
    void* __restrict__ C0,
    unsigned short* __restrict__ Ck,
    unsigned short* __restrict__ Vout,
    const float* __restrict__ qs, const float* __restrict__ ks,
    int K)
{
    __shared__ __align__(16) unsigned char smem[32768];
    __bf16* As = (__bf16*)smem;             // [128][64] swizzled granules
    __bf16* Bs = (__bf16*)(smem + 16384);   // [128][64]

    int tid = threadIdx.x, lane = tid & 63, wave = tid >> 6;
    int quad = lane >> 4, l15 = lane & 15;
    int m0 = blockIdx.y * 128, n0 = blockIdx.x * 128;
    int wm = (wave & 1) * 64, wn = (wave >> 1) * 64;
    f32x4 acc[4][4] = {};

    // staging: lane covers row (slab + p*8 + lane>>3), granule (lane&7);
    // source col pre-swizzled so LDS slot w holds granule w^(row&7).
    const int srow8 = lane >> 3;            // row-within-8 == (row&7)
    const int w7    = lane & 7;
    const int swz   = ((w7 ^ srow8) << 3);  // halfs
    const unsigned short* gA = A  + (size_t)(m0 + wave * 32 + srow8) * K + swz;
    const unsigned short* gB = Bt + (size_t)(n0 + wave * 32 + srow8) * K + swz;
    const size_t r8 = (size_t)8 * K;

    const int nsteps = K >> 6;
    for (int s = 0; s < nsteps; ++s) {
#pragma unroll
        for (int p = 0; p < 4; ++p)
            gl_lds16(gA + p * r8, &As[(wave * 32 + p * 8) * 64]);
#pragma unroll
        for (int p = 0; p < 4; ++p)
            gl_lds16(gB + p * r8, &Bs[(wave * 32 + p * 8) * 64]);
        gA += 64; gB += 64;
        __syncthreads();
#pragma unroll
        for (int kk = 0; kk < 2; ++kk) {
            bf16x8 af[4], bfv[4];
#pragma unroll
            for (int i = 0; i < 4; ++i) {
                int row = wm + i * 16 + l15;
                int g = ((kk << 2) + quad) ^ (l15 & 7);
                af[i] = *(const bf16x8*)&As[row * 64 + (g << 3)];
            }
#pragma unroll
            for (int j = 0; j < 4; ++j) {
                int row = wn + j * 16 + l15;
                int g = ((kk << 2) + quad) ^ (l15 & 7);
                bfv[j] = *(const bf16x8*)&Bs[row * 64 + (g << 3)];
            }
#pragma unroll
            for (int i = 0; i < 4; ++i)
#pragma unroll
                for (int j = 0; j < 4; ++j)
                    acc[i][j] = mfma16(af[i], bfv[j], acc[i][j]);
        }
        __syncthreads();
    }

    if (MODE == 2) {
#pragma unroll
        for (int i = 0; i < 4; ++i)
#pragma unroll
            for (int j = 0; j < 4; ++j) {
                int row = m0 + wm + i * 16 + quad * 4;
                int col = n0 + wn + j * 16 + l15;
                size_t base = (size_t)row * 1024 + col;
#pragma unroll
                for (int r = 0; r < 4; ++r)
                    ((float*)C0)[base + (size_t)r * 1024] = acc[i][j][r];
            }
        return;
    }

    // ----- fused QKV epilogues (wave's 64 cols = one head) -----
    if (n0 >= 2048) {
        // V: per-wave 64x64 (tok x d) -> LDS transpose (aliases staging smem;
        // safe: K-loop's final barrier drained all reads) -> uint2 stores.
        unsigned short* tileL = (unsigned short*)smem + wave * 4096;
        int hv = (n0 + wn - 2048) >> 6;
        int bidx = m0 >> 11;                        // block never straddles
        int tok0w = (m0 + wm) & 2047;
        size_t vbase = (size_t)((((bidx << 4) + hv) << 6)) * 2056;
#pragma unroll
        for (int i = 0; i < 4; ++i)
#pragma unroll
            for (int j = 0; j < 4; ++j) {
                int d = j * 16 + l15;
                int tk = (i * 16 + quad * 4) ^ ((d & 7) << 3);
                unsigned u01 = (unsigned)f2h(acc[i][j][0])
                             | ((unsigned)f2h(acc[i][j][1]) << 16);
                unsigned u23 = (unsigned)f2h(acc[i][j][2])
                             | ((unsigned)f2h(acc[i][j][3]) << 16);
                *(unsigned*)&tileL[d * 64 + tk]     = u01;
                *(unsigned*)&tileL[d * 64 + tk + 2] = u23;
            }
        // same-wave read-out (compiler orders via lgkmcnt)
#pragma unroll
        for (int rr = 0; rr < 16; ++rr) {
            int d = rr * 4 + quad;
            uint2 val = *(const uint2*)
                &tileL[d * 64 + ((l15 * 4) ^ ((d & 7) << 3))];
            *(uint2*)(Vout + vbase + (size_t)d * 2056 + tok0w + l15 * 4) = val;
        }
        return;
    }

    const bool isQ = (n0 < 1024);
    float sc[4];
#pragma unroll
    for (int j = 0; j < 4; ++j) {
        float s = isQ ? qs[j * 16 + l15] : ks[j * 16 + l15];
        sc[j] = isQ ? s * (0.125f * 1.44269504088896f) : s;
    }
    unsigned short* outp = isQ ? (unsigned short*)C0 : Ck;
    const int coln0 = isQ ? n0 : (n0 - 1024);
#pragma unroll
    for (int i = 0; i < 4; ++i)
#pragma unroll
        for (int r = 0; r < 4; ++r) {
            float ss = 0.f;
#pragma unroll
            for (int j = 0; j < 4; ++j) ss += acc[i][j][r] * acc[i][j][r];
            ss += __shfl_xor(ss, 1); ss += __shfl_xor(ss, 2);
            ss += __shfl_xor(ss, 4); ss += __shfl_xor(ss, 8);
            float mul = rsqrtf(ss + 1e-12f);
            size_t rowbase = (size_t)(m0 + wm + i * 16 + quad * 4 + r) * 1024
                           + coln0 + wn + l15;
#pragma unroll
            for (int j = 0; j < 4; ++j) {
                float v = acc[i][j][r];
                outp[rowbase + j * 16] = f2b(v * mul * sc[j]);
            }
        }
}

// -- null kv: l2norm k + k_scale (bf16); v -> VtG col 2048; zero 2049..2055 -
__global__ __launch_bounds__(256) void nullkv_kernel(
    const float* __restrict__ null_kv, const float* __restrict__ k_scale,
    unsigned short* __restrict__ knull, unsigned short* __restrict__ Vt)
{
    int wave = threadIdx.x >> 6, lane = threadIdx.x & 63;
    int h = blockIdx.x * 4 + wave;
    int idx = (h << 6) + lane;
    float kvl = null_kv[idx];
    float ss = kvl * kvl;
#pragma unroll
    for (int off = 1; off < 64; off <<= 1) ss += __shfl_xor(ss, off);
    knull[idx] = f2b(kvl * rsqrtf(ss + 1e-12f) * k_scale[lane]);
    unsigned short vn = f2h(null_kv[1024 + idx]);
#pragma unroll
    for (int b = 0; b < 4; ++b)
        Vt[((size_t)(((b << 4) + h) << 6) + lane) * 2056 + 2048] = vn;
    // zero pad cols 2049..2055 of all 4096 rows
    int t = blockIdx.x * 256 + threadIdx.x;        // 0..1023
#pragma unroll
    for (int rr = 0; rr < 4; ++rr) {
        size_t row = (size_t)t * 4 + rr;
#pragma unroll
        for (int c = 0; c < 7; ++c)
            Vt[row * 2056 + 2049 + c] = 0;
    }
}

// ---------------- attention: BM=128 (4 waves x 32 rows), BT=64 tokens ------
// (unchanged from R13 — see that round's header for the layout derivation)
__global__ __launch_bounds__(256, 4) void attn_kernel(
    const unsigned short* __restrict__ qn,    // [B*2048,1024] l2norm*qs*log2e/8
    const unsigned short* __restrict__ kvK,   // [B*2048,1024] k bf16 (l2norm)
    const unsigned short* __restrict__ knull, // [16*64] bf16
    const unsigned short* __restrict__ Vt,    // [64bh][64d][2056tok] f16
    const int* __restrict__ mask,             // [B*2048]
    unsigned short* __restrict__ ao)          // [B*2048,1024]
{
    __shared__ __bf16    Kt[2][64 * 64];
    __shared__ _Float16  Vl[2][64 * 64];
    __shared__ __align__(16) float biasLds[2][64];

    const int tid = threadIdx.x, lane = tid & 63, wave = tid >> 6;
    const int quad = lane >> 4, l15 = lane & 15;
    const int bh = blockIdx.x;                 // (b,h): K/V sharers same XCD
    const int b = bh >> 4, h = bh & 15;
    const int mbase = blockIdx.y * 128 + wave * 32;
    const size_t rowoff = (size_t)b * 2048;

    bf16x8 qf[2][2];                           // B-operand fragments
#pragma unroll
    for (int rg = 0; rg < 2; ++rg)
#pragma unroll
        for (int ks = 0; ks < 2; ++ks)
            qf[rg][ks] = *(const bf16x8*)
                &qn[((rowoff + mbase + rg * 16 + l15) << 10) + (h << 6) + ks * 32 + quad * 8];

    const int t8  = lane >> 3;
    const int w7  = lane & 7;
    const int ksc = (w7 ^ t8) << 3;            // (r&7)==t8 since base%8==0
    const size_t vrow0 = ((size_t)bh << 6);    // first VtG row of this (b,h)

    const int r0v = wave * 16 + t8;            // LDS row (p=0) = V d-row
    const int r1v = wave * 16 + 8 + t8;        // LDS row (p=1)
    auto Tof = [](int r) {
        return ((r >> 5) << 5) | (((r >> 2) & 3) << 3)
             | (((r >> 4) & 1) << 2) | (r & 3);
    };
    const int T0 = Tof(r0v), T1 = Tof(r1v);    // T1 != 0 always

    // strength-reduced staging pointers (point at NEXT tile to issue)
    const unsigned short* kp0 = kvK + ((rowoff + T0) << 10) + (h << 6) + ksc;
    const unsigned short* kp1 = kvK + ((rowoff + T1) << 10) + (h << 6) + ksc;
    const unsigned short* vp0 = Vt + (vrow0 + r0v) * 2056 + ((w7 ^ t8) << 3);
    const unsigned short* vp1 = Vt + (vrow0 + r1v) * 2056 + ((w7 ^ t8) << 3);

    auto issueFast = [&](int bf) {
        gl_lds16(kp0, &Kt[bf][(wave * 16) * 64]);
        gl_lds16(kp1, &Kt[bf][(wave * 16 + 8) * 64]);
        gl_lds16(vp0, &Vl[bf][(wave * 16) * 64]);
        gl_lds16(vp1, &Vl[bf][(wave * 16 + 8) * 64]);
        kp0 += 65536; kp1 += 65536;            // 64 tokens * 1024 halfs
        vp0 += 64; vp1 += 64;                  // 8 granules
    };
    auto issue32 = [&](int bf) {               // tokens 2048..2111
        const unsigned short* kc =
            kvK + ((rowoff + 2047) << 10) + (h << 6) + ksc;   // finite clamp
        const unsigned short* s0 = (T0 == 0) ? knull + (h << 6) + ksc : kc;
        gl_lds16(s0, &Kt[bf][(wave * 16) * 64]);
        gl_lds16(kc, &Kt[bf][(wave * 16 + 8) * 64]);
        gl_lds16(Vt + (vrow0 + r0v) * 2056 + 2048, &Vl[bf][(wave * 16) * 64]);
        gl_lds16(Vt + (vrow0 + r1v) * 2056 + 2048, &Vl[bf][(wave * 16 + 8) * 64]);
    };
    auto biasFor = [&](int nt) -> float {      // wave 0 only
        int j = (nt << 6) + lane;
        float bv = -512.f;
        if (j < 2048) { if (mask[(b << 11) + j] != 0) bv = 0.f; }
        else if (j == 2048) bv = 0.f;
        return bv;
    };

    const uintv4 onesu = { 0x3c003c00u, 0x3c003c00u, 0x3c003c00u, 0x3c003c00u };
    const f16x8 ones = __builtin_bit_cast(f16x8, onesu);

    f32x4 O[2][4] = {};
    f32x4 rsacc[2] = {};

    issueFast(0);
    float bcur = 0.f;
    if (wave == 0) bcur = biasFor(0);

    for (int nt = 0; nt < 33; ++nt) {
        const int buf = nt & 1;
        if (wave == 0) biasLds[buf][lane] = bcur;
        __syncthreads();   // drains gl_lds(nt); bias(nt) visible; prev buf free
        if (nt < 31) {     // issue AFTER barrier: overlaps compute below
            issueFast(buf ^ 1);
            if (wave == 0) bcur = biasFor(nt + 1);
        } else if (nt == 31) {
            issue32(buf ^ 1);
            if (wave == 0) bcur = biasFor(32);
        }

#pragma unroll
        for (int g = 0; g < 2; ++g) {
            // --- QK^T: only one kf pair (8 VGPRs) live at a time ---
            float4 b0 = *(const float4*)&biasLds[buf][(g << 5) + (quad << 3)];
            float4 b1 = *(const float4*)&biasLds[buf][(g << 5) + (quad << 3) + 4];
            f32x4 s[2][2];
#pragma unroll
            for (int rg = 0; rg < 2; ++rg) {
                s[rg][0] = f32x4{ b0.x, b0.y, b0.z, b0.w };
                s[rg][1] = f32x4{ b1.x, b1.y, b1.z, b1.w };
            }
#pragma unroll
            for (int t = 0; t < 2; ++t) {
                const __bf16* kb = &Kt[buf][((g * 2 + t) * 16 + l15) * 64];
                bf16x8 k0 = *(const bf16x8*)&kb[(quad ^ (l15 & 7)) << 3];
                bf16x8 k1 = *(const bf16x8*)&kb[((4 + quad) ^ (l15 & 7)) << 3];
#pragma unroll
                for (int rg = 0; rg < 2; ++rg) {
                    s[rg][t] = mfma16(k0, qf[rg][0], s[rg][t]);
                    s[rg][t] = mfma16(k1, qf[rg][1], s[rg][t]);
                }
            }
            // --- V fragments: one b128 each, XOR-swizzled slot ---
            f16x8 vf8[4];
#pragma unroll
            for (int dt = 0; dt < 4; ++dt)
                vf8[dt] = *(const f16x8*)
                    &Vl[buf][(dt * 16 + l15) * 64
                             + ((((g << 2) + quad) ^ (l15 & 7)) << 3)];
            // --- exp2 + pack + PV (+ denominator via ones-MFMA) ---
#pragma unroll
            for (int rg = 0; rg < 2; ++rg) {
                float e0 = __builtin_amdgcn_exp2f(s[rg][0][0]);
                float e1 = __builtin_amdgcn_exp2f(s[rg][0][1]);
                float e2 = __builtin_amdgcn_exp2f(s[rg][0][2]);
                float e3 = __builtin_amdgcn_exp2f(s[rg][0][3]);
                float e4 = __builtin_amdgcn_exp2f(s[rg][1][0]);
                float e5 = __builtin_amdgcn_exp2f(s[rg][1][1]);
                float e6 = __builtin_amdgcn_exp2f(s[rg][1][2]);
                float e7 = __builtin_amdgcn_exp2f(s[rg][1][3]);
                uintv4 pu = { pk16(e0, e1), pk16(e2, e3),
                              pk16(e4, e5), pk16(e6, e7) };
                f16x8 p = __builtin_bit_cast(f16x8, pu);
                rsacc[rg] = mfma16h(p, ones, rsacc[rg]);
#pragma unroll
                for (int dt = 0; dt < 4; ++dt)
                    O[rg][dt] = mfma16h(p, vf8[dt], O[rg][dt]);
            }
        }
    }

    // rsacc[rg][r] = denom for q-row rg*16 + quad*4 + r (same lane as O rows)
#pragma unroll
    for (int rg = 0; rg < 2; ++rg) {
        float inv[4];
#pragma unroll
        for (int r = 0; r < 4; ++r) inv[r] = 1.f / rsacc[rg][r];
#pragma unroll
        for (int dt = 0; dt < 4; ++dt) {
            size_t base = ((rowoff + mbase + rg * 16 + quad * 4) << 10)
                        + (h << 6) + dt * 16 + l15;
#pragma unroll
            for (int r = 0; r < 4; ++r)
                ao[base + ((size_t)r << 10)] = f2b(O[rg][dt][r] * inv[r]);
        }
    }
}

// ---------------------------------------------------------------------------
extern "C" void kernel_launch(void* const* d_in, const int* in_sizes, int n_in,
                              void* d_out, int out_size, void* d_ws, size_t ws_size,
                              hipStream_t stream)
{
    const float* x       = (const float*)d_in[0];
    const int*   mask    = (const int*)d_in[1];
    const float* gamma   = (const float*)d_in[2];
    const float* null_kv = (const float*)d_in[3];
    const float* Wq      = (const float*)d_in[4];
    const float* Wkv     = (const float*)d_in[5];
    const float* q_scale = (const float*)d_in[6];
    const float* k_scale = (const float*)d_in[7];
    const float* Wout    = (const float*)d_in[8];

    // Workspace map (~70.07 MiB; ao aliases xn; WoutT lives in the dead q
    // buffer, written by a transpose launched AFTER attn):
    //   0        xn/ao    16 MiB
    //   16 MiB   q        16 MiB   (post-attn: first 2 MiB reused as WoutT)
    //   32 MiB   kvK      16 MiB   [tok][1024] bf16
    //   48 MiB   VtG      16.0625 MiB = 4096 rows * 4112 B ([bh][d][2056] f16)
    //   +VtG     WqkvT    6 MiB    [3072][1024] bf16 (Wq rows 0..1023,
    //                              Wkv K rows 1024..2047, V rows 2048..3071)
    //   +6 MiB   knull    2 KiB
    char* ws = (char*)d_ws;
    const size_t VTG_OFF   = (size_t)48u << 20;
    const size_t VTG_SIZE  = (size_t)4096 * 4112;
    const size_t WQKV_OFF  = VTG_OFF + VTG_SIZE;
    const size_t WQKV_SIZE = (size_t)3072 * 1024 * 2;
    unsigned short* xn    = (unsigned short*)(ws);
    unsigned short* ao    = xn;                                    // reuse
    unsigned short* q     = (unsigned short*)(ws + ((size_t)16u << 20));
    unsigned short* WoutT = q;                                     // post-attn
    unsigned short* kvK   = (unsigned short*)(ws + ((size_t)32u << 20));
    unsigned short* VtG   = (unsigned short*)(ws + VTG_OFF);
    unsigned short* WqkvT = (unsigned short*)(ws + WQKV_OFF);
    unsigned short* knull = (unsigned short*)(ws + WQKV_OFF + WQKV_SIZE);

    dim3 tb(32, 8);
    transpose_f2b<<<dim3(32, 32), tb, 0, stream>>>(Wq,  WqkvT,             1024, 1024);
    transpose_f2b<<<dim3(64, 32), tb, 0, stream>>>(Wkv, WqkvT + (1u << 20), 1024, 2048);

    ln_kernel<<<8192, 256, 0, stream>>>(x, gamma, xn);

    nullkv_kernel<<<4, 256, 0, stream>>>(null_kv, k_scale, knull, VtG);

    // fused QKV projection: bx<8 Q, 8..15 K, >=16 V
    gemm_bt<0><<<dim3(24, 64), 256, 0, stream>>>(xn, WqkvT, q, kvK, VtG,
                                                 q_scale, k_scale, 1024);

    attn_kernel<<<dim3(64, 16), 256, 0, stream>>>(q, kvK, knull, VtG, mask, ao);

    // q is dead now; put WoutT there and run the out-projection
    transpose_f2b<<<dim3(32, 32), tb, 0, stream>>>(Wout, WoutT, 1024, 1024);

    gemm_bt<2><<<dim3(8, 64), 256, 0, stream>>>(ao, WoutT, d_out, nullptr, nullptr,
                                                nullptr, nullptr, 1024);
}

// Round 6
// 286.189 us; speedup vs baseline: 1.0663x; 1.0116x over previous
//
#include <hip/hip_runtime.h>
#include <hip/hip_bf16.h>
#include <stdint.h>

// ---------------------------------------------------------------------------
// fp32 inputs; mask int32; fp32 output. Internal pipeline bf16/f16.
// LayerNorm -> ONE fused QKV GEMM (Wq|Wkv concatenated) with l2norm epilogues
//   (V emitted f16 TRANSPOSED [b,h][d][token], null token at col 2048)
//   -> flash attn (R11 structure) -> out proj GEMM.
// R15: (a) QKV GEMM grid is 1-D ROLE-ORDERED: bids 0..511 Q, 512..1023 K,
//      1024..1535 V. Launch order ~ completion order -> K/V written LAST,
//      restoring R13's L2 recency for attn (R14's interleaved Q/K/V writes
//      cost attn +6.6us of L2-miss latency at identical FETCH_SIZE).
//      (b) GEMM 2-phase dbuf pipeline, un-confounded: R12's regression was
//      the separate 32KB Vx on top of 64KB dbuf (96KB -> 1 block/CU). Now
//      Vx aliases the dead staging LDS: dbuf = 64KB total, still 2 blocks/CU.
//      stage(next)->compute(cur)->1 barrier: the vmcnt drain lands after
//      ~400cyc of MFMA instead of stalling cold at loop top. BK=64 + T2
//      swizzle retained from R14.
//      attn/LN/transpose/nullkv unchanged.
// ---------------------------------------------------------------------------

using f32x4  = __attribute__((ext_vector_type(4))) float;
using bf16x8 = __attribute__((ext_vector_type(8))) __bf16;
using f16x8  = __attribute__((ext_vector_type(8))) _Float16;
using uintv4 = __attribute__((ext_vector_type(4))) unsigned int;

__device__ __forceinline__ unsigned short f2b(float f) {
    unsigned u = __float_as_uint(f);
    u += 0x7fffu + ((u >> 16) & 1u);   // RNE
    return (unsigned short)(u >> 16);
}
__device__ __forceinline__ unsigned short f2h(float f) {   // RNE f32->f16
    return __builtin_bit_cast(unsigned short, (_Float16)f);
}
__device__ __forceinline__ f32x4 mfma16(bf16x8 a, bf16x8 b, f32x4 c) {
    return __builtin_amdgcn_mfma_f32_16x16x32_bf16(a, b, c, 0, 0, 0);
}
__device__ __forceinline__ f32x4 mfma16h(f16x8 a, f16x8 b, f32x4 c) {
    return __builtin_amdgcn_mfma_f32_16x16x32_f16(a, b, c, 0, 0, 0);
}
// packed f32x2 -> f16x2 (RTZ), returned as the raw 32-bit pattern
__device__ __forceinline__ unsigned pk16(float a, float b) {
    return __builtin_bit_cast(unsigned, __builtin_amdgcn_cvt_pkrtz(a, b));
}
// async global->LDS, 16B/lane; LDS dst = wave-uniform base + lane*16
__device__ __forceinline__ void gl_lds16(const void* g, void* l) {
    __builtin_amdgcn_global_load_lds(
        (const __attribute__((address_space(1))) unsigned int*)g,
        (__attribute__((address_space(3))) unsigned int*)l, 16, 0, 0);
}

// ------------- weight transpose + fp32->bf16: in[R][C] -> out[C][R] --------
__global__ __launch_bounds__(256) void transpose_f2b(
    const float* __restrict__ in, unsigned short* __restrict__ out,
    int R, int C)
{
    __shared__ unsigned short t[32][33];
    int tx = threadIdx.x, ty = threadIdx.y;       // (32,8)
    int c = blockIdx.x * 32 + tx;
#pragma unroll
    for (int i = 0; i < 4; ++i) {
        int r = blockIdx.y * 32 + ty + i * 8;
        t[ty + i * 8][tx] = f2b(in[(size_t)r * C + c]);
    }
    __syncthreads();
    int r2 = blockIdx.y * 32 + tx;
#pragma unroll
    for (int i = 0; i < 4; ++i) {
        int c2 = blockIdx.x * 32 + ty + i * 8;
        out[(size_t)c2 * R + r2] = t[tx][ty + i * 8];
    }
}

// -------- LayerNorm: one row (1024 fp32) per block of 256 -> bf16 ----------
__global__ __launch_bounds__(256) void ln_kernel(
    const float* __restrict__ x, const float* __restrict__ gamma,
    unsigned short* __restrict__ xn)
{
    int row = blockIdx.x, tid = threadIdx.x;
    int wave = tid >> 6, lane = tid & 63;
    float4 raw = *(const float4*)(x + ((size_t)row << 10) + (tid << 2));
    float v[4] = { raw.x, raw.y, raw.z, raw.w };
    float s  = v[0] + v[1] + v[2] + v[3];
    float s2 = v[0]*v[0] + v[1]*v[1] + v[2]*v[2] + v[3]*v[3];
#pragma unroll
    for (int off = 1; off < 64; off <<= 1) {
        s  += __shfl_xor(s, off);
        s2 += __shfl_xor(s2, off);
    }
    __shared__ float ps[4], ps2[4], sh[2];
    if (lane == 0) { ps[wave] = s; ps2[wave] = s2; }
    __syncthreads();
    if (tid == 0) {
        float S  = ps[0] + ps[1] + ps[2] + ps[3];
        float S2 = ps2[0] + ps2[1] + ps2[2] + ps2[3];
        float mu  = S * (1.f / 1024.f);
        float var = S2 * (1.f / 1024.f) - mu * mu;
        sh[0] = mu; sh[1] = rsqrtf(var + 1e-5f);
    }
    __syncthreads();
    float mu = sh[0], rstd = sh[1];
    float4 g4 = *(const float4*)(gamma + (tid << 2));
    float g[4] = { g4.x, g4.y, g4.z, g4.w };
    unsigned short o[4];
#pragma unroll
    for (int i = 0; i < 4; ++i) o[i] = f2b((v[i] - mu) * rstd * g[i]);
    uint2 out;
    out.x = (unsigned)o[0] | ((unsigned)o[1] << 16);
    out.y = (unsigned)o[2] | ((unsigned)o[3] << 16);
    *(uint2*)(xn + ((size_t)row << 10) + (tid << 2)) = out;
}

// ---- GEMM C=A[8192,K]*Bt[N,K]^T, 128x128 tile, BK=64, swizzled dbuf LDS --
// 2-phase: stage(next, buf^1) -> compute(buf) -> ONE barrier per K-step.
// LDS [row][64] granule g at slot g^(row&7), staged via pre-swizzled global
// source; ds_read_b128 <=2-way. 1-D grid, role-partitioned:
// MODE 0: bid<512: Q l2norm*qs*0.125*log2e -> C0; 512..1023: K l2norm*ks
//         -> Ck; >=1024: V raw f16 transposed -> Vout[b*16+h][d][tok]
//         (V LDS transpose tile aliases dead staging smem).
// MODE 2: 512 blocks, plain f32 store -> C0.
template<int MODE>
__global__ __launch_bounds__(256, 2) void gemm_bt(
    const unsigned short* __restrict__ A,
    const unsigned short* __restrict__ Bt,
    void* __restrict__ C0,
    unsigned short* __restrict__ Ck,
    unsigned short* __restrict__ Vout,
    const float* __restrict__ qs, const float* __restrict__ ks,
    int K)
{
    __shared__ __align__(16) unsigned char smem[65536];
    __bf16* As = (__bf16*)smem;             // [2][128][64] swizzled granules
    __bf16* Bs = (__bf16*)(smem + 32768);

    int tid = threadIdx.x, lane = tid & 63, wave = tid >> 6;
    int quad = lane >> 4, l15 = lane & 15;
    const int bid = blockIdx.x;
    const int role = bid >> 9;              // 0=Q 1=K 2=V (MODE 0)
    const int rr_  = bid & 511;
    int m0 = (rr_ >> 3) * 128;
    int n0 = role * 1024 + (rr_ & 7) * 128;
    int wm = (wave & 1) * 64, wn = (wave >> 1) * 64;
    f32x4 acc[4][4] = {};

    // staging: lane covers row (slab + p*8 + lane>>3), granule (lane&7);
    // source col pre-swizzled so LDS slot w holds granule w^(row&7).
    const int srow8 = lane >> 3;            // row-within-8 == (row&7)
    const int w7    = lane & 7;
    const int swz   = ((w7 ^ srow8) << 3);  // halfs
    const unsigned short* gA = A  + (size_t)(m0 + wave * 32 + srow8) * K + swz;
    const unsigned short* gB = Bt + (size_t)(n0 + wave * 32 + srow8) * K + swz;
    const size_t r8 = (size_t)8 * K;

    auto stage = [&](int bf) {
        __bf16* Ab = As + bf * 8192;
        __bf16* Bb = Bs + bf * 8192;
#pragma unroll
        for (int p = 0; p < 4; ++p)
            gl_lds16(gA + p * r8, &Ab[(wave * 32 + p * 8) * 64]);
#pragma unroll
        for (int p = 0; p < 4; ++p)
            gl_lds16(gB + p * r8, &Bb[(wave * 32 + p * 8) * 64]);
        gA += 64; gB += 64;
    };

    stage(0);
    __syncthreads();                        // tile 0 resident
    const int nsteps = K >> 6;
    for (int s = 0; s < nsteps; ++s) {
        const int cur = s & 1;
        if (s + 1 < nsteps) stage(cur ^ 1); // prefetch flies under compute
        const __bf16* Ab = As + cur * 8192;
        const __bf16* Bb = Bs + cur * 8192;
#pragma unroll
        for (int kk = 0; kk < 2; ++kk) {
            bf16x8 af[4], bfv[4];
#pragma unroll
            for (int i = 0; i < 4; ++i) {
                int row = wm + i * 16 + l15;
                int g = ((kk << 2) + quad) ^ (l15 & 7);
                af[i] = *(const bf16x8*)&Ab[row * 64 + (g << 3)];
            }
#pragma unroll
            for (int j = 0; j < 4; ++j) {
                int row = wn + j * 16 + l15;
                int g = ((kk << 2) + quad) ^ (l15 & 7);
                bfv[j] = *(const bf16x8*)&Bb[row * 64 + (g << 3)];
            }
#pragma unroll
            for (int i = 0; i < 4; ++i)
#pragma unroll
                for (int j = 0; j < 4; ++j)
                    acc[i][j] = mfma16(af[i], bfv[j], acc[i][j]);
        }
        __syncthreads();  // drains prefetch (flew under MFMA) + frees cur
    }

    if (MODE == 2) {
#pragma unroll
        for (int i = 0; i < 4; ++i)
#pragma unroll
            for (int j = 0; j < 4; ++j) {
                int row = m0 + wm + i * 16 + quad * 4;
                int col = n0 + wn + j * 16 + l15;
                size_t base = (size_t)row * 1024 + col;
#pragma unroll
                for (int r = 0; r < 4; ++r)
                    ((float*)C0)[base + (size_t)r * 1024] = acc[i][j][r];
            }
        return;
    }

    // ----- fused QKV epilogues (wave's 64 cols = one head) -----
    if (n0 >= 2048) {
        // V: per-wave 64x64 (tok x d) -> LDS transpose (aliases staging smem;
        // safe: final K-loop barrier drained all reads) -> uint2 stores.
        unsigned short* tileL = (unsigned short*)smem + wave * 4096;
        int hv = (n0 + wn - 2048) >> 6;
        int bidx = m0 >> 11;                        // block never straddles
        int tok0w = (m0 + wm) & 2047;
        size_t vbase = (size_t)((((bidx << 4) + hv) << 6)) * 2056;
#pragma unroll
        for (int i = 0; i < 4; ++i)
#pragma unroll
            for (int j = 0; j < 4; ++j) {
                int d = j * 16 + l15;
                int tk = (i * 16 + quad * 4) ^ ((d & 7) << 3);
                unsigned u01 = (unsigned)f2h(acc[i][j][0])
                             | ((unsigned)f2h(acc[i][j][1]) << 16);
                unsigned u23 = (unsigned)f2h(acc[i][j][2])
                             | ((unsigned)f2h(acc[i][j][3]) << 16);
                *(unsigned*)&tileL[d * 64 + tk]     = u01;
                *(unsigned*)&tileL[d * 64 + tk + 2] = u23;
            }
        // same-wave read-out (compiler orders via lgkmcnt)
#pragma unroll
        for (int rrr = 0; rrr < 16; ++rrr) {
            int d = rrr * 4 + quad;
            uint2 val = *(const uint2*)
                &tileL[d * 64 + ((l15 * 4) ^ ((d & 7) << 3))];
            *(uint2*)(Vout + vbase + (size_t)d * 2056 + tok0w + l15 * 4) = val;
        }
        return;
    }

    const bool isQ = (n0 < 1024);
    float sc[4];
#pragma unroll
    for (int j = 0; j < 4; ++j) {
        float s = isQ ? qs[j * 16 + l15] : ks[j * 16 + l15];
        sc[j] = isQ ? s * (0.125f * 1.44269504088896f) : s;
    }
    unsigned short* outp = isQ ? (unsigned short*)C0 : Ck;
    const int coln0 = isQ ? n0 : (n0 - 1024);
#pragma unroll
    for (int i = 0; i < 4; ++i)
#pragma unroll
        for (int r = 0; r < 4; ++r) {
            float ss = 0.f;
#pragma unroll
            for (int j = 0; j < 4; ++j) ss += acc[i][j][r] * acc[i][j][r];
            ss += __shfl_xor(ss, 1); ss += __shfl_xor(ss, 2);
            ss += __shfl_xor(ss, 4); ss += __shfl_xor(ss, 8);
            float mul = rsqrtf(ss + 1e-12f);
            size_t rowbase = (size_t)(m0 + wm + i * 16 + quad * 4 + r) * 1024
                           + coln0 + wn + l15;
#pragma unroll
            for (int j = 0; j < 4; ++j) {
                float v = acc[i][j][r];
                outp[rowbase + j * 16] = f2b(v * mul * sc[j]);
            }
        }
}

// -- null kv: l2norm k + k_scale (bf16); v -> VtG col 2048; zero 2049..2055 -
__global__ __launch_bounds__(256) void nullkv_kernel(
    const float* __restrict__ null_kv, const float* __restrict__ k_scale,
    unsigned short* __restrict__ knull, unsigned short* __restrict__ Vt)
{
    int wave = threadIdx.x >> 6, lane = threadIdx.x & 63;
    int h = blockIdx.x * 4 + wave;
    int idx = (h << 6) + lane;
    float kvl = null_kv[idx];
    float ss = kvl * kvl;
#pragma unroll
    for (int off = 1; off < 64; off <<= 1) ss += __shfl_xor(ss, off);
    knull[idx] = f2b(kvl * rsqrtf(ss + 1e-12f) * k_scale[lane]);
    unsigned short vn = f2h(null_kv[1024 + idx]);
#pragma unroll
    for (int b = 0; b < 4; ++b)
        Vt[((size_t)(((b << 4) + h) << 6) + lane) * 2056 + 2048] = vn;
    // zero pad cols 2049..2055 of all 4096 rows
    int t = blockIdx.x * 256 + threadIdx.x;        // 0..1023
#pragma unroll
    for (int rr = 0; rr < 4; ++rr) {
        size_t row = (size_t)t * 4 + rr;
#pragma unroll
        for (int c = 0; c < 7; ++c)
            Vt[row * 2056 + 2049 + c] = 0;
    }
}

// ---------------- attention: BM=128 (4 waves x 32 rows), BT=64 tokens ------
// (unchanged from R13 — see that round's header for the layout derivation)
__global__ __launch_bounds__(256, 4) void attn_kernel(
    const unsigned short* __restrict__ qn,    // [B*2048,1024] l2norm*qs*log2e/8
    const unsigned short* __restrict__ kvK,   // [B*2048,1024] k bf16 (l2norm)
    const unsigned short* __restrict__ knull, // [16*64] bf16
    const unsigned short* __restrict__ Vt,    // [64bh][64d][2056tok] f16
    const int* __restrict__ mask,             // [B*2048]
    unsigned short* __restrict__ ao)          // [B*2048,1024]
{
    __shared__ __bf16    Kt[2][64 * 64];
    __shared__ _Float16  Vl[2][64 * 64];
    __shared__ __align__(16) float biasLds[2][64];

    const int tid = threadIdx.x, lane = tid & 63, wave = tid >> 6;
    const int quad = lane >> 4, l15 = lane & 15;
    const int bh = blockIdx.x;                 // (b,h): K/V sharers same XCD
    const int b = bh >> 4, h = bh & 15;
    const int mbase = blockIdx.y * 128 + wave * 32;
    const size_t rowoff = (size_t)b * 2048;

    bf16x8 qf[2][2];                           // B-operand fragments
#pragma unroll
    for (int rg = 0; rg < 2; ++rg)
#pragma unroll
        for (int ks = 0; ks < 2; ++ks)
            qf[rg][ks] = *(const bf16x8*)
                &qn[((rowoff + mbase + rg * 16 + l15) << 10) + (h << 6) + ks * 32 + quad * 8];

    const int t8  = lane >> 3;
    const int w7  = lane & 7;
    const int ksc = (w7 ^ t8) << 3;            // (r&7)==t8 since base%8==0
    const size_t vrow0 = ((size_t)bh << 6);    // first VtG row of this (b,h)

    const int r0v = wave * 16 + t8;            // LDS row (p=0) = V d-row
    const int r1v = wave * 16 + 8 + t8;        // LDS row (p=1)
    auto Tof = [](int r) {
        return ((r >> 5) << 5) | (((r >> 2) & 3) << 3)
             | (((r >> 4) & 1) << 2) | (r & 3);
    };
    const int T0 = Tof(r0v), T1 = Tof(r1v);    // T1 != 0 always

    // strength-reduced staging pointers (point at NEXT tile to issue)
    const unsigned short* kp0 = kvK + ((rowoff + T0) << 10) + (h << 6) + ksc;
    const unsigned short* kp1 = kvK + ((rowoff + T1) << 10) + (h << 6) + ksc;
    const unsigned short* vp0 = Vt + (vrow0 + r0v) * 2056 + ((w7 ^ t8) << 3);
    const unsigned short* vp1 = Vt + (vrow0 + r1v) * 2056 + ((w7 ^ t8) << 3);

    auto issueFast = [&](int bf) {
        gl_lds16(kp0, &Kt[bf][(wave * 16) * 64]);
        gl_lds16(kp1, &Kt[bf][(wave * 16 + 8) * 64]);
        gl_lds16(vp0, &Vl[bf][(wave * 16) * 64]);
        gl_lds16(vp1, &Vl[bf][(wave * 16 + 8) * 64]);
        kp0 += 65536; kp1 += 65536;            // 64 tokens * 1024 halfs
        vp0 += 64; vp1 += 64;                  // 8 granules
    };
    auto issue32 = [&](int bf) {               // tokens 2048..2111
        const unsigned short* kc =
            kvK + ((rowoff + 2047) << 10) + (h << 6) + ksc;   // finite clamp
        const unsigned short* s0 = (T0 == 0) ? knull + (h << 6) + ksc : kc;
        gl_lds16(s0, &Kt[bf][(wave * 16) * 64]);
        gl_lds16(kc, &Kt[bf][(wave * 16 + 8) * 64]);
        gl_lds16(Vt + (vrow0 + r0v) * 2056 + 2048, &Vl[bf][(wave * 16) * 64]);
        gl_lds16(Vt + (vrow0 + r1v) * 2056 + 2048, &Vl[bf][(wave * 16 + 8) * 64]);
    };
    auto biasFor = [&](int nt) -> float {      // wave 0 only
        int j = (nt << 6) + lane;
        float bv = -512.f;
        if (j < 2048) { if (mask[(b << 11) + j] != 0) bv = 0.f; }
        else if (j == 2048) bv = 0.f;
        return bv;
    };

    const uintv4 onesu = { 0x3c003c00u, 0x3c003c00u, 0x3c003c00u, 0x3c003c00u };
    const f16x8 ones = __builtin_bit_cast(f16x8, onesu);

    f32x4 O[2][4] = {};
    f32x4 rsacc[2] = {};

    issueFast(0);
    float bcur = 0.f;
    if (wave == 0) bcur = biasFor(0);

    for (int nt = 0; nt < 33; ++nt) {
        const int buf = nt & 1;
        if (wave == 0) biasLds[buf][lane] = bcur;
        __syncthreads();   // drains gl_lds(nt); bias(nt) visible; prev buf free
        if (nt < 31) {     // issue AFTER barrier: overlaps compute below
            issueFast(buf ^ 1);
            if (wave == 0) bcur = biasFor(nt + 1);
        } else if (nt == 31) {
            issue32(buf ^ 1);
            if (wave == 0) bcur = biasFor(32);
        }

#pragma unroll
        for (int g = 0; g < 2; ++g) {
            // --- QK^T: only one kf pair (8 VGPRs) live at a time ---
            float4 b0 = *(const float4*)&biasLds[buf][(g << 5) + (quad << 3)];
            float4 b1 = *(const float4*)&biasLds[buf][(g << 5) + (quad << 3) + 4];
            f32x4 s[2][2];
#pragma unroll
            for (int rg = 0; rg < 2; ++rg) {
                s[rg][0] = f32x4{ b0.x, b0.y, b0.z, b0.w };
                s[rg][1] = f32x4{ b1.x, b1.y, b1.z, b1.w };
            }
#pragma unroll
            for (int t = 0; t < 2; ++t) {
                const __bf16* kb = &Kt[buf][((g * 2 + t) * 16 + l15) * 64];
                bf16x8 k0 = *(const bf16x8*)&kb[(quad ^ (l15 & 7)) << 3];
                bf16x8 k1 = *(const bf16x8*)&kb[((4 + quad) ^ (l15 & 7)) << 3];
#pragma unroll
                for (int rg = 0; rg < 2; ++rg) {
                    s[rg][t] = mfma16(k0, qf[rg][0], s[rg][t]);
                    s[rg][t] = mfma16(k1, qf[rg][1], s[rg][t]);
                }
            }
            // --- V fragments: one b128 each, XOR-swizzled slot ---
            f16x8 vf8[4];
#pragma unroll
            for (int dt = 0; dt < 4; ++dt)
                vf8[dt] = *(const f16x8*)
                    &Vl[buf][(dt * 16 + l15) * 64
                             + ((((g << 2) + quad) ^ (l15 & 7)) << 3)];
            // --- exp2 + pack + PV (+ denominator via ones-MFMA) ---
#pragma unroll
            for (int rg = 0; rg < 2; ++rg) {
                float e0 = __builtin_amdgcn_exp2f(s[rg][0][0]);
                float e1 = __builtin_amdgcn_exp2f(s[rg][0][1]);
                float e2 = __builtin_amdgcn_exp2f(s[rg][0][2]);
                float e3 = __builtin_amdgcn_exp2f(s[rg][0][3]);
                float e4 = __builtin_amdgcn_exp2f(s[rg][1][0]);
                float e5 = __builtin_amdgcn_exp2f(s[rg][1][1]);
                float e6 = __builtin_amdgcn_exp2f(s[rg][1][2]);
                float e7 = __builtin_amdgcn_exp2f(s[rg][1][3]);
                uintv4 pu = { pk16(e0, e1), pk16(e2, e3),
                              pk16(e4, e5), pk16(e6, e7) };
                f16x8 p = __builtin_bit_cast(f16x8, pu);
                rsacc[rg] = mfma16h(p, ones, rsacc[rg]);
#pragma unroll
                for (int dt = 0; dt < 4; ++dt)
                    O[rg][dt] = mfma16h(p, vf8[dt], O[rg][dt]);
            }
        }
    }

    // rsacc[rg][r] = denom for q-row rg*16 + quad*4 + r (same lane as O rows)
#pragma unroll
    for (int rg = 0; rg < 2; ++rg) {
        float inv[4];
#pragma unroll
        for (int r = 0; r < 4; ++r) inv[r] = 1.f / rsacc[rg][r];
#pragma unroll
        for (int dt = 0; dt < 4; ++dt) {
            size_t base = ((rowoff + mbase + rg * 16 + quad * 4) << 10)
                        + (h << 6) + dt * 16 + l15;
#pragma unroll
            for (int r = 0; r < 4; ++r)
                ao[base + ((size_t)r << 10)] = f2b(O[rg][dt][r] * inv[r]);
        }
    }
}

// ---------------------------------------------------------------------------
extern "C" void kernel_launch(void* const* d_in, const int* in_sizes, int n_in,
                              void* d_out, int out_size, void* d_ws, size_t ws_size,
                              hipStream_t stream)
{
    const float* x       = (const float*)d_in[0];
    const int*   mask    = (const int*)d_in[1];
    const float* gamma   = (const float*)d_in[2];
    const float* null_kv = (const float*)d_in[3];
    const float* Wq      = (const float*)d_in[4];
    const float* Wkv     = (const float*)d_in[5];
    const float* q_scale = (const float*)d_in[6];
    const float* k_scale = (const float*)d_in[7];
    const float* Wout    = (const float*)d_in[8];

    // Workspace map (~70.07 MiB; ao aliases xn; WoutT lives in the dead q
    // buffer, written by a transpose launched AFTER attn):
    //   0        xn/ao    16 MiB
    //   16 MiB   q        16 MiB   (post-attn: first 2 MiB reused as WoutT)
    //   32 MiB   kvK      16 MiB   [tok][1024] bf16
    //   48 MiB   VtG      16.0625 MiB = 4096 rows * 4112 B ([bh][d][2056] f16)
    //   +VtG     WqkvT    6 MiB    [3072][1024] bf16 (Wq rows 0..1023,
    //                              Wkv K rows 1024..2047, V rows 2048..3071)
    //   +6 MiB   knull    2 KiB
    char* ws = (char*)d_ws;
    const size_t VTG_OFF   = (size_t)48u << 20;
    const size_t VTG_SIZE  = (size_t)4096 * 4112;
    const size_t WQKV_OFF  = VTG_OFF + VTG_SIZE;
    const size_t WQKV_SIZE = (size_t)3072 * 1024 * 2;
    unsigned short* xn    = (unsigned short*)(ws);
    unsigned short* ao    = xn;                                    // reuse
    unsigned short* q     = (unsigned short*)(ws + ((size_t)16u << 20));
    unsigned short* WoutT = q;                                     // post-attn
    unsigned short* kvK   = (unsigned short*)(ws + ((size_t)32u << 20));
    unsigned short* VtG   = (unsigned short*)(ws + VTG_OFF);
    unsigned short* WqkvT = (unsigned short*)(ws + WQKV_OFF);
    unsigned short* knull = (unsigned short*)(ws + WQKV_OFF + WQKV_SIZE);

    dim3 tb(32, 8);
    transpose_f2b<<<dim3(32, 32), tb, 0, stream>>>(Wq,  WqkvT,              1024, 1024);
    transpose_f2b<<<dim3(64, 32), tb, 0, stream>>>(Wkv, WqkvT + (1u << 20), 1024, 2048);

    ln_kernel<<<8192, 256, 0, stream>>>(x, gamma, xn);

    nullkv_kernel<<<4, 256, 0, stream>>>(null_kv, k_scale, knull, VtG);

    // fused QKV projection, role-ordered 1-D grid: Q (0..511) computed first,
    // K (512..1023), V (1024..1535) last -> K/V freshest in L2 for attn
    gemm_bt<0><<<dim3(1536), 256, 0, stream>>>(xn, WqkvT, q, kvK, VtG,
                                               q_scale, k_scale, 1024);

    attn_kernel<<<dim3(64, 16), 256, 0, stream>>>(q, kvK, knull, VtG, mask, ao);

    // q is dead now; put WoutT there and run the out-projection
    transpose_f2b<<<dim3(32, 32), tb, 0, stream>>>(Wout, WoutT, 1024, 1024);

    gemm_bt<2><<<dim3(512), 256, 0, stream>>>(ao, WoutT, d_out, nullptr, nullptr,
                                              nullptr, nullptr, 1024);
}

// Round 7
// 261.441 us; speedup vs baseline: 1.1672x; 1.0947x over previous
//
#include <hip/hip_runtime.h>
#include <hip/hip_bf16.h>
#include <stdint.h>

// ---------------------------------------------------------------------------
// fp32 inputs; mask int32; fp32 output. Internal pipeline bf16/f16.
// LayerNorm -> ONE fused QKV GEMM (Wq|Wkv concatenated) with l2norm epilogues
//   (V emitted f16 TRANSPOSED [b,h][d][token], null token at col 2048)
//   -> flash attn (R11 structure) -> out proj GEMM.
// R16: per-role XCD-chunked tile swizzle in the GEMMs. R15's role-ordered
//   1-D grid put the 8 n-blocks sharing an A m-panel on 8 DIFFERENT XCDs
//   (consecutive bids, round-robin XCD) -> per-XCD L2s don't share -> each
//   A panel fetched ~8x: FETCH_SIZE 195MB vs ~54MB ideal, QKV GEMM 83us
//   L2-miss-bound (MfmaUtil 25%). Fix: local=bid&511,
//   swz=(local&7)*64+(local>>3) (bijective rotation; 512%8==0): XCD x owns
//   m-tiles [x*8,(x+1)*8) x all n -> working set = 1 A-panel (256KB,
//   streamed) + 2MB role weights < 4MB L2; each panel fetched by ONE XCD.
//   Role time-order (Q->K->V last) preserved -> attn L2 recency kept.
//   Same swizzle for the out-proj (same 64x8 tile space).
//   dbuf 2-phase + BK=64 + T2 swizzle retained; attn/LN/nullkv unchanged.
// ---------------------------------------------------------------------------

using f32x4  = __attribute__((ext_vector_type(4))) float;
using bf16x8 = __attribute__((ext_vector_type(8))) __bf16;
using f16x8  = __attribute__((ext_vector_type(8))) _Float16;
using uintv4 = __attribute__((ext_vector_type(4))) unsigned int;

__device__ __forceinline__ unsigned short f2b(float f) {
    unsigned u = __float_as_uint(f);
    u += 0x7fffu + ((u >> 16) & 1u);   // RNE
    return (unsigned short)(u >> 16);
}
__device__ __forceinline__ unsigned short f2h(float f) {   // RNE f32->f16
    return __builtin_bit_cast(unsigned short, (_Float16)f);
}
__device__ __forceinline__ f32x4 mfma16(bf16x8 a, bf16x8 b, f32x4 c) {
    return __builtin_amdgcn_mfma_f32_16x16x32_bf16(a, b, c, 0, 0, 0);
}
__device__ __forceinline__ f32x4 mfma16h(f16x8 a, f16x8 b, f32x4 c) {
    return __builtin_amdgcn_mfma_f32_16x16x32_f16(a, b, c, 0, 0, 0);
}
// packed f32x2 -> f16x2 (RTZ), returned as the raw 32-bit pattern
__device__ __forceinline__ unsigned pk16(float a, float b) {
    return __builtin_bit_cast(unsigned, __builtin_amdgcn_cvt_pkrtz(a, b));
}
// async global->LDS, 16B/lane; LDS dst = wave-uniform base + lane*16
__device__ __forceinline__ void gl_lds16(const void* g, void* l) {
    __builtin_amdgcn_global_load_lds(
        (const __attribute__((address_space(1))) unsigned int*)g,
        (__attribute__((address_space(3))) unsigned int*)l, 16, 0, 0);
}

// ------------- weight transpose + fp32->bf16: in[R][C] -> out[C][R] --------
__global__ __launch_bounds__(256) void transpose_f2b(
    const float* __restrict__ in, unsigned short* __restrict__ out,
    int R, int C)
{
    __shared__ unsigned short t[32][33];
    int tx = threadIdx.x, ty = threadIdx.y;       // (32,8)
    int c = blockIdx.x * 32 + tx;
#pragma unroll
    for (int i = 0; i < 4; ++i) {
        int r = blockIdx.y * 32 + ty + i * 8;
        t[ty + i * 8][tx] = f2b(in[(size_t)r * C + c]);
    }
    __syncthreads();
    int r2 = blockIdx.y * 32 + tx;
#pragma unroll
    for (int i = 0; i < 4; ++i) {
        int c2 = blockIdx.x * 32 + ty + i * 8;
        out[(size_t)c2 * R + r2] = t[tx][ty + i * 8];
    }
}

// -------- LayerNorm: one row (1024 fp32) per block of 256 -> bf16 ----------
__global__ __launch_bounds__(256) void ln_kernel(
    const float* __restrict__ x, const float* __restrict__ gamma,
    unsigned short* __restrict__ xn)
{
    int row = blockIdx.x, tid = threadIdx.x;
    int wave = tid >> 6, lane = tid & 63;
    float4 raw = *(const float4*)(x + ((size_t)row << 10) + (tid << 2));
    float v[4] = { raw.x, raw.y, raw.z, raw.w };
    float s  = v[0] + v[1] + v[2] + v[3];
    float s2 = v[0]*v[0] + v[1]*v[1] + v[2]*v[2] + v[3]*v[3];
#pragma unroll
    for (int off = 1; off < 64; off <<= 1) {
        s  += __shfl_xor(s, off);
        s2 += __shfl_xor(s2, off);
    }
    __shared__ float ps[4], ps2[4], sh[2];
    if (lane == 0) { ps[wave] = s; ps2[wave] = s2; }
    __syncthreads();
    if (tid == 0) {
        float S  = ps[0] + ps[1] + ps[2] + ps[3];
        float S2 = ps2[0] + ps2[1] + ps2[2] + ps2[3];
        float mu  = S * (1.f / 1024.f);
        float var = S2 * (1.f / 1024.f) - mu * mu;
        sh[0] = mu; sh[1] = rsqrtf(var + 1e-5f);
    }
    __syncthreads();
    float mu = sh[0], rstd = sh[1];
    float4 g4 = *(const float4*)(gamma + (tid << 2));
    float g[4] = { g4.x, g4.y, g4.z, g4.w };
    unsigned short o[4];
#pragma unroll
    for (int i = 0; i < 4; ++i) o[i] = f2b((v[i] - mu) * rstd * g[i]);
    uint2 out;
    out.x = (unsigned)o[0] | ((unsigned)o[1] << 16);
    out.y = (unsigned)o[2] | ((unsigned)o[3] << 16);
    *(uint2*)(xn + ((size_t)row << 10) + (tid << 2)) = out;
}

// ---- GEMM C=A[8192,K]*Bt[N,K]^T, 128x128 tile, BK=64, swizzled dbuf LDS --
// 2-phase: stage(next, buf^1) -> compute(buf) -> ONE barrier per K-step.
// Tile mapping: local=bid&511 rotated to swz=(local&7)*64+(local>>3) so each
// XCD owns a contiguous band of 8 m-tiles (see R16 header). LDS [row][64]
// granule g at slot g^(row&7), staged pre-swizzled; ds_read_b128 <=2-way.
// MODE 0: role=bid>>9: 0 Q l2norm*qs*0.125*log2e -> C0; 1 K l2norm*ks -> Ck;
//         2 V raw f16 transposed -> Vout (LDS tile aliases staging smem).
// MODE 2: 512 blocks, plain f32 store -> C0.
template<int MODE>
__global__ __launch_bounds__(256, 2) void gemm_bt(
    const unsigned short* __restrict__ A,
    const unsigned short* __restrict__ Bt,
    void* __restrict__ C0,
    unsigned short* __restrict__ Ck,
    unsigned short* __restrict__ Vout,
    const float* __restrict__ qs, const float* __restrict__ ks,
    int K)
{
    __shared__ __align__(16) unsigned char smem[65536];
    __bf16* As = (__bf16*)smem;             // [2][128][64] swizzled granules
    __bf16* Bs = (__bf16*)(smem + 32768);

    int tid = threadIdx.x, lane = tid & 63, wave = tid >> 6;
    int quad = lane >> 4, l15 = lane & 15;
    const int bid = blockIdx.x;
    const int role = bid >> 9;              // 0=Q 1=K 2=V (MODE 0)
    const int local = bid & 511;
    const int swztile = ((local & 7) << 6) | (local >> 3);  // XCD-chunked
    int m0 = (swztile >> 3) * 128;
    int n0 = role * 1024 + (swztile & 7) * 128;
    int wm = (wave & 1) * 64, wn = (wave >> 1) * 64;
    f32x4 acc[4][4] = {};

    // staging: lane covers row (slab + p*8 + lane>>3), granule (lane&7);
    // source col pre-swizzled so LDS slot w holds granule w^(row&7).
    const int srow8 = lane >> 3;            // row-within-8 == (row&7)
    const int w7    = lane & 7;
    const int swz   = ((w7 ^ srow8) << 3);  // halfs
    const unsigned short* gA = A  + (size_t)(m0 + wave * 32 + srow8) * K + swz;
    const unsigned short* gB = Bt + (size_t)(n0 + wave * 32 + srow8) * K + swz;
    const size_t r8 = (size_t)8 * K;

    auto stage = [&](int bf) {
        __bf16* Ab = As + bf * 8192;
        __bf16* Bb = Bs + bf * 8192;
#pragma unroll
        for (int p = 0; p < 4; ++p)
            gl_lds16(gA + p * r8, &Ab[(wave * 32 + p * 8) * 64]);
#pragma unroll
        for (int p = 0; p < 4; ++p)
            gl_lds16(gB + p * r8, &Bb[(wave * 32 + p * 8) * 64]);
        gA += 64; gB += 64;
    };

    stage(0);
    __syncthreads();                        // tile 0 resident
    const int nsteps = K >> 6;
    for (int s = 0; s < nsteps; ++s) {
        const int cur = s & 1;
        if (s + 1 < nsteps) stage(cur ^ 1); // prefetch flies under compute
        const __bf16* Ab = As + cur * 8192;
        const __bf16* Bb = Bs + cur * 8192;
#pragma unroll
        for (int kk = 0; kk < 2; ++kk) {
            bf16x8 af[4], bfv[4];
#pragma unroll
            for (int i = 0; i < 4; ++i) {
                int row = wm + i * 16 + l15;
                int g = ((kk << 2) + quad) ^ (l15 & 7);
                af[i] = *(const bf16x8*)&Ab[row * 64 + (g << 3)];
            }
#pragma unroll
            for (int j = 0; j < 4; ++j) {
                int row = wn + j * 16 + l15;
                int g = ((kk << 2) + quad) ^ (l15 & 7);
                bfv[j] = *(const bf16x8*)&Bb[row * 64 + (g << 3)];
            }
#pragma unroll
            for (int i = 0; i < 4; ++i)
#pragma unroll
                for (int j = 0; j < 4; ++j)
                    acc[i][j] = mfma16(af[i], bfv[j], acc[i][j]);
        }
        __syncthreads();  // drains prefetch (flew under MFMA) + frees cur
    }

    if (MODE == 2) {
#pragma unroll
        for (int i = 0; i < 4; ++i)
#pragma unroll
            for (int j = 0; j < 4; ++j) {
                int row = m0 + wm + i * 16 + quad * 4;
                int col = n0 + wn + j * 16 + l15;
                size_t base = (size_t)row * 1024 + col;
#pragma unroll
                for (int r = 0; r < 4; ++r)
                    ((float*)C0)[base + (size_t)r * 1024] = acc[i][j][r];
            }
        return;
    }

    // ----- fused QKV epilogues (wave's 64 cols = one head) -----
    if (n0 >= 2048) {
        // V: per-wave 64x64 (tok x d) -> LDS transpose (aliases staging smem;
        // safe: final K-loop barrier drained all reads) -> uint2 stores.
        unsigned short* tileL = (unsigned short*)smem + wave * 4096;
        int hv = (n0 + wn - 2048) >> 6;
        int bidx = m0 >> 11;                        // block never straddles
        int tok0w = (m0 + wm) & 2047;
        size_t vbase = (size_t)((((bidx << 4) + hv) << 6)) * 2056;
#pragma unroll
        for (int i = 0; i < 4; ++i)
#pragma unroll
            for (int j = 0; j < 4; ++j) {
                int d = j * 16 + l15;
                int tk = (i * 16 + quad * 4) ^ ((d & 7) << 3);
                unsigned u01 = (unsigned)f2h(acc[i][j][0])
                             | ((unsigned)f2h(acc[i][j][1]) << 16);
                unsigned u23 = (unsigned)f2h(acc[i][j][2])
                             | ((unsigned)f2h(acc[i][j][3]) << 16);
                *(unsigned*)&tileL[d * 64 + tk]     = u01;
                *(unsigned*)&tileL[d * 64 + tk + 2] = u23;
            }
        // same-wave read-out (compiler orders via lgkmcnt)
#pragma unroll
        for (int rrr = 0; rrr < 16; ++rrr) {
            int d = rrr * 4 + quad;
            uint2 val = *(const uint2*)
                &tileL[d * 64 + ((l15 * 4) ^ ((d & 7) << 3))];
            *(uint2*)(Vout + vbase + (size_t)d * 2056 + tok0w + l15 * 4) = val;
        }
        return;
    }

    const bool isQ = (n0 < 1024);
    float sc[4];
#pragma unroll
    for (int j = 0; j < 4; ++j) {
        float s = isQ ? qs[j * 16 + l15] : ks[j * 16 + l15];
        sc[j] = isQ ? s * (0.125f * 1.44269504088896f) : s;
    }
    unsigned short* outp = isQ ? (unsigned short*)C0 : Ck;
    const int coln0 = isQ ? n0 : (n0 - 1024);
#pragma unroll
    for (int i = 0; i < 4; ++i)
#pragma unroll
        for (int r = 0; r < 4; ++r) {
            float ss = 0.f;
#pragma unroll
            for (int j = 0; j < 4; ++j) ss += acc[i][j][r] * acc[i][j][r];
            ss += __shfl_xor(ss, 1); ss += __shfl_xor(ss, 2);
            ss += __shfl_xor(ss, 4); ss += __shfl_xor(ss, 8);
            float mul = rsqrtf(ss + 1e-12f);
            size_t rowbase = (size_t)(m0 + wm + i * 16 + quad * 4 + r) * 1024
                           + coln0 + wn + l15;
#pragma unroll
            for (int j = 0; j < 4; ++j) {
                float v = acc[i][j][r];
                outp[rowbase + j * 16] = f2b(v * mul * sc[j]);
            }
        }
}

// -- null kv: l2norm k + k_scale (bf16); v -> VtG col 2048; zero 2049..2055 -
__global__ __launch_bounds__(256) void nullkv_kernel(
    const float* __restrict__ null_kv, const float* __restrict__ k_scale,
    unsigned short* __restrict__ knull, unsigned short* __restrict__ Vt)
{
    int wave = threadIdx.x >> 6, lane = threadIdx.x & 63;
    int h = blockIdx.x * 4 + wave;
    int idx = (h << 6) + lane;
    float kvl = null_kv[idx];
    float ss = kvl * kvl;
#pragma unroll
    for (int off = 1; off < 64; off <<= 1) ss += __shfl_xor(ss, off);
    knull[idx] = f2b(kvl * rsqrtf(ss + 1e-12f) * k_scale[lane]);
    unsigned short vn = f2h(null_kv[1024 + idx]);
#pragma unroll
    for (int b = 0; b < 4; ++b)
        Vt[((size_t)(((b << 4) + h) << 6) + lane) * 2056 + 2048] = vn;
    // zero pad cols 2049..2055 of all 4096 rows
    int t = blockIdx.x * 256 + threadIdx.x;        // 0..1023
#pragma unroll
    for (int rr = 0; rr < 4; ++rr) {
        size_t row = (size_t)t * 4 + rr;
#pragma unroll
        for (int c = 0; c < 7; ++c)
            Vt[row * 2056 + 2049 + c] = 0;
    }
}

// ---------------- attention: BM=128 (4 waves x 32 rows), BT=64 tokens ------
// (unchanged from R13 — see that round's header for the layout derivation)
__global__ __launch_bounds__(256, 4) void attn_kernel(
    const unsigned short* __restrict__ qn,    // [B*2048,1024] l2norm*qs*log2e/8
    const unsigned short* __restrict__ kvK,   // [B*2048,1024] k bf16 (l2norm)
    const unsigned short* __restrict__ knull, // [16*64] bf16
    const unsigned short* __restrict__ Vt,    // [64bh][64d][2056tok] f16
    const int* __restrict__ mask,             // [B*2048]
    unsigned short* __restrict__ ao)          // [B*2048,1024]
{
    __shared__ __bf16    Kt[2][64 * 64];
    __shared__ _Float16  Vl[2][64 * 64];
    __shared__ __align__(16) float biasLds[2][64];

    const int tid = threadIdx.x, lane = tid & 63, wave = tid >> 6;
    const int quad = lane >> 4, l15 = lane & 15;
    const int bh = blockIdx.x;                 // (b,h): K/V sharers same XCD
    const int b = bh >> 4, h = bh & 15;
    const int mbase = blockIdx.y * 128 + wave * 32;
    const size_t rowoff = (size_t)b * 2048;

    bf16x8 qf[2][2];                           // B-operand fragments
#pragma unroll
    for (int rg = 0; rg < 2; ++rg)
#pragma unroll
        for (int ks = 0; ks < 2; ++ks)
            qf[rg][ks] = *(const bf16x8*)
                &qn[((rowoff + mbase + rg * 16 + l15) << 10) + (h << 6) + ks * 32 + quad * 8];

    const int t8  = lane >> 3;
    const int w7  = lane & 7;
    const int ksc = (w7 ^ t8) << 3;            // (r&7)==t8 since base%8==0
    const size_t vrow0 = ((size_t)bh << 6);    // first VtG row of this (b,h)

    const int r0v = wave * 16 + t8;            // LDS row (p=0) = V d-row
    const int r1v = wave * 16 + 8 + t8;        // LDS row (p=1)
    auto Tof = [](int r) {
        return ((r >> 5) << 5) | (((r >> 2) & 3) << 3)
             | (((r >> 4) & 1) << 2) | (r & 3);
    };
    const int T0 = Tof(r0v), T1 = Tof(r1v);    // T1 != 0 always

    // strength-reduced staging pointers (point at NEXT tile to issue)
    const unsigned short* kp0 = kvK + ((rowoff + T0) << 10) + (h << 6) + ksc;
    const unsigned short* kp1 = kvK + ((rowoff + T1) << 10) + (h << 6) + ksc;
    const unsigned short* vp0 = Vt + (vrow0 + r0v) * 2056 + ((w7 ^ t8) << 3);
    const unsigned short* vp1 = Vt + (vrow0 + r1v) * 2056 + ((w7 ^ t8) << 3);

    auto issueFast = [&](int bf) {
        gl_lds16(kp0, &Kt[bf][(wave * 16) * 64]);
        gl_lds16(kp1, &Kt[bf][(wave * 16 + 8) * 64]);
        gl_lds16(vp0, &Vl[bf][(wave * 16) * 64]);
        gl_lds16(vp1, &Vl[bf][(wave * 16 + 8) * 64]);
        kp0 += 65536; kp1 += 65536;            // 64 tokens * 1024 halfs
        vp0 += 64; vp1 += 64;                  // 8 granules
    };
    auto issue32 = [&](int bf) {               // tokens 2048..2111
        const unsigned short* kc =
            kvK + ((rowoff + 2047) << 10) + (h << 6) + ksc;   // finite clamp
        const unsigned short* s0 = (T0 == 0) ? knull + (h << 6) + ksc : kc;
        gl_lds16(s0, &Kt[bf][(wave * 16) * 64]);
        gl_lds16(kc, &Kt[bf][(wave * 16 + 8) * 64]);
        gl_lds16(Vt + (vrow0 + r0v) * 2056 + 2048, &Vl[bf][(wave * 16) * 64]);
        gl_lds16(Vt + (vrow0 + r1v) * 2056 + 2048, &Vl[bf][(wave * 16 + 8) * 64]);
    };
    auto biasFor = [&](int nt) -> float {      // wave 0 only
        int j = (nt << 6) + lane;
        float bv = -512.f;
        if (j < 2048) { if (mask[(b << 11) + j] != 0) bv = 0.f; }
        else if (j == 2048) bv = 0.f;
        return bv;
    };

    const uintv4 onesu = { 0x3c003c00u, 0x3c003c00u, 0x3c003c00u, 0x3c003c00u };
    const f16x8 ones = __builtin_bit_cast(f16x8, onesu);

    f32x4 O[2][4] = {};
    f32x4 rsacc[2] = {};

    issueFast(0);
    float bcur = 0.f;
    if (wave == 0) bcur = biasFor(0);

    for (int nt = 0; nt < 33; ++nt) {
        const int buf = nt & 1;
        if (wave == 0) biasLds[buf][lane] = bcur;
        __syncthreads();   // drains gl_lds(nt); bias(nt) visible; prev buf free
        if (nt < 31) {     // issue AFTER barrier: overlaps compute below
            issueFast(buf ^ 1);
            if (wave == 0) bcur = biasFor(nt + 1);
        } else if (nt == 31) {
            issue32(buf ^ 1);
            if (wave == 0) bcur = biasFor(32);
        }

#pragma unroll
        for (int g = 0; g < 2; ++g) {
            // --- QK^T: only one kf pair (8 VGPRs) live at a time ---
            float4 b0 = *(const float4*)&biasLds[buf][(g << 5) + (quad << 3)];
            float4 b1 = *(const float4*)&biasLds[buf][(g << 5) + (quad << 3) + 4];
            f32x4 s[2][2];
#pragma unroll
            for (int rg = 0; rg < 2; ++rg) {
                s[rg][0] = f32x4{ b0.x, b0.y, b0.z, b0.w };
                s[rg][1] = f32x4{ b1.x, b1.y, b1.z, b1.w };
            }
#pragma unroll
            for (int t = 0; t < 2; ++t) {
                const __bf16* kb = &Kt[buf][((g * 2 + t) * 16 + l15) * 64];
                bf16x8 k0 = *(const bf16x8*)&kb[(quad ^ (l15 & 7)) << 3];
                bf16x8 k1 = *(const bf16x8*)&kb[((4 + quad) ^ (l15 & 7)) << 3];
#pragma unroll
                for (int rg = 0; rg < 2; ++rg) {
                    s[rg][t] = mfma16(k0, qf[rg][0], s[rg][t]);
                    s[rg][t] = mfma16(k1, qf[rg][1], s[rg][t]);
                }
            }
            // --- V fragments: one b128 each, XOR-swizzled slot ---
            f16x8 vf8[4];
#pragma unroll
            for (int dt = 0; dt < 4; ++dt)
                vf8[dt] = *(const f16x8*)
                    &Vl[buf][(dt * 16 + l15) * 64
                             + ((((g << 2) + quad) ^ (l15 & 7)) << 3)];
            // --- exp2 + pack + PV (+ denominator via ones-MFMA) ---
#pragma unroll
            for (int rg = 0; rg < 2; ++rg) {
                float e0 = __builtin_amdgcn_exp2f(s[rg][0][0]);
                float e1 = __builtin_amdgcn_exp2f(s[rg][0][1]);
                float e2 = __builtin_amdgcn_exp2f(s[rg][0][2]);
                float e3 = __builtin_amdgcn_exp2f(s[rg][0][3]);
                float e4 = __builtin_amdgcn_exp2f(s[rg][1][0]);
                float e5 = __builtin_amdgcn_exp2f(s[rg][1][1]);
                float e6 = __builtin_amdgcn_exp2f(s[rg][1][2]);
                float e7 = __builtin_amdgcn_exp2f(s[rg][1][3]);
                uintv4 pu = { pk16(e0, e1), pk16(e2, e3),
                              pk16(e4, e5), pk16(e6, e7) };
                f16x8 p = __builtin_bit_cast(f16x8, pu);
                rsacc[rg] = mfma16h(p, ones, rsacc[rg]);
#pragma unroll
                for (int dt = 0; dt < 4; ++dt)
                    O[rg][dt] = mfma16h(p, vf8[dt], O[rg][dt]);
            }
        }
    }

    // rsacc[rg][r] = denom for q-row rg*16 + quad*4 + r (same lane as O rows)
#pragma unroll
    for (int rg = 0; rg < 2; ++rg) {
        float inv[4];
#pragma unroll
        for (int r = 0; r < 4; ++r) inv[r] = 1.f / rsacc[rg][r];
#pragma unroll
        for (int dt = 0; dt < 4; ++dt) {
            size_t base = ((rowoff + mbase + rg * 16 + quad * 4) << 10)
                        + (h << 6) + dt * 16 + l15;
#pragma unroll
            for (int r = 0; r < 4; ++r)
                ao[base + ((size_t)r << 10)] = f2b(O[rg][dt][r] * inv[r]);
        }
    }
}

// ---------------------------------------------------------------------------
extern "C" void kernel_launch(void* const* d_in, const int* in_sizes, int n_in,
                              void* d_out, int out_size, void* d_ws, size_t ws_size,
                              hipStream_t stream)
{
    const float* x       = (const float*)d_in[0];
    const int*   mask    = (const int*)d_in[1];
    const float* gamma   = (const float*)d_in[2];
    const float* null_kv = (const float*)d_in[3];
    const float* Wq      = (const float*)d_in[4];
    const float* Wkv     = (const float*)d_in[5];
    const float* q_scale = (const float*)d_in[6];
    const float* k_scale = (const float*)d_in[7];
    const float* Wout    = (const float*)d_in[8];

    // Workspace map (~70.07 MiB; ao aliases xn; WoutT lives in the dead q
    // buffer, written by a transpose launched AFTER attn):
    //   0        xn/ao    16 MiB
    //   16 MiB   q        16 MiB   (post-attn: first 2 MiB reused as WoutT)
    //   32 MiB   kvK      16 MiB   [tok][1024] bf16
    //   48 MiB   VtG      16.0625 MiB = 4096 rows * 4112 B ([bh][d][2056] f16)
    //   +VtG     WqkvT    6 MiB    [3072][1024] bf16 (Wq rows 0..1023,
    //                              Wkv K rows 1024..2047, V rows 2048..3071)
    //   +6 MiB   knull    2 KiB
    char* ws = (char*)d_ws;
    const size_t VTG_OFF   = (size_t)48u << 20;
    const size_t VTG_SIZE  = (size_t)4096 * 4112;
    const size_t WQKV_OFF  = VTG_OFF + VTG_SIZE;
    const size_t WQKV_SIZE = (size_t)3072 * 1024 * 2;
    unsigned short* xn    = (unsigned short*)(ws);
    unsigned short* ao    = xn;                                    // reuse
    unsigned short* q     = (unsigned short*)(ws + ((size_t)16u << 20));
    unsigned short* WoutT = q;                                     // post-attn
    unsigned short* kvK   = (unsigned short*)(ws + ((size_t)32u << 20));
    unsigned short* VtG   = (unsigned short*)(ws + VTG_OFF);
    unsigned short* WqkvT = (unsigned short*)(ws + WQKV_OFF);
    unsigned short* knull = (unsigned short*)(ws + WQKV_OFF + WQKV_SIZE);

    dim3 tb(32, 8);
    transpose_f2b<<<dim3(32, 32), tb, 0, stream>>>(Wq,  WqkvT,              1024, 1024);
    transpose_f2b<<<dim3(64, 32), tb, 0, stream>>>(Wkv, WqkvT + (1u << 20), 1024, 2048);

    ln_kernel<<<8192, 256, 0, stream>>>(x, gamma, xn);

    nullkv_kernel<<<4, 256, 0, stream>>>(null_kv, k_scale, knull, VtG);

    // fused QKV projection, role-ordered 1-D grid with per-role XCD-chunked
    // tile swizzle: Q (0..511) first, K, then V last -> K/V freshest for attn
    gemm_bt<0><<<dim3(1536), 256, 0, stream>>>(xn, WqkvT, q, kvK, VtG,
                                               q_scale, k_scale, 1024);

    attn_kernel<<<dim3(64, 16), 256, 0, stream>>>(q, kvK, knull, VtG, mask, ao);

    // q is dead now; put WoutT there and run the out-projection
    transpose_f2b<<<dim3(32, 32), tb, 0, stream>>>(Wout, WoutT, 1024, 1024);

    gemm_bt<2><<<dim3(512), 256, 0, stream>>>(ao, WoutT, d_out, nullptr, nullptr,
                                              nullptr, nullptr, 1024);
}

// Round 8
// 257.812 us; speedup vs baseline: 1.1836x; 1.0141x over previous
//
#include <hip/hip_runtime.h>
#include <hip/hip_bf16.h>
#include <stdint.h>

// ---------------------------------------------------------------------------
// fp32 inputs; mask int32; fp32 output. Internal pipeline bf16/f16.
// LayerNorm -> ONE fused QKV GEMM (Wq|Wkv concatenated) with l2norm epilogues
//   (V emitted f16 TRANSPOSED [b,h][d][token], null token at col 2048)
//   -> flash attn (R11 structure) -> out proj GEMM.
// R17: (a) dispatch-count cut 8->6: Wq/Wkv transposes + nullkv merged into
//      ONE prep kernel (uniform per-block branch, same (32,8) shape). Each
//      serialized graph-node boundary costs ~3-4us; attn/QKV/out unchanged
//      in content. WoutT transpose stays post-attn (aliases q).
//      (b) T5 s_setprio(1/0) around attn's QK and PV MFMA clusters: 2.6
//      independent blocks/CU give the cross-wave phase diversity where
//      setprio pays (m191 regime, not m190 lockstep).
// R16: per-role XCD-chunked tile swizzle in GEMMs (FETCH 195->~60MB, QKV
//      out of top-5). R11-R15 history in git.
// ---------------------------------------------------------------------------

using f32x4  = __attribute__((ext_vector_type(4))) float;
using bf16x8 = __attribute__((ext_vector_type(8))) __bf16;
using f16x8  = __attribute__((ext_vector_type(8))) _Float16;
using uintv4 = __attribute__((ext_vector_type(4))) unsigned int;

__device__ __forceinline__ unsigned short f2b(float f) {
    unsigned u = __float_as_uint(f);
    u += 0x7fffu + ((u >> 16) & 1u);   // RNE
    return (unsigned short)(u >> 16);
}
__device__ __forceinline__ unsigned short f2h(float f) {   // RNE f32->f16
    return __builtin_bit_cast(unsigned short, (_Float16)f);
}
__device__ __forceinline__ f32x4 mfma16(bf16x8 a, bf16x8 b, f32x4 c) {
    return __builtin_amdgcn_mfma_f32_16x16x32_bf16(a, b, c, 0, 0, 0);
}
__device__ __forceinline__ f32x4 mfma16h(f16x8 a, f16x8 b, f32x4 c) {
    return __builtin_amdgcn_mfma_f32_16x16x32_f16(a, b, c, 0, 0, 0);
}
// packed f32x2 -> f16x2 (RTZ), returned as the raw 32-bit pattern
__device__ __forceinline__ unsigned pk16(float a, float b) {
    return __builtin_bit_cast(unsigned, __builtin_amdgcn_cvt_pkrtz(a, b));
}
// async global->LDS, 16B/lane; LDS dst = wave-uniform base + lane*16
__device__ __forceinline__ void gl_lds16(const void* g, void* l) {
    __builtin_amdgcn_global_load_lds(
        (const __attribute__((address_space(1))) unsigned int*)g,
        (__attribute__((address_space(3))) unsigned int*)l, 16, 0, 0);
}

// ------------- weight transpose + fp32->bf16: in[R][C] -> out[C][R] --------
__global__ __launch_bounds__(256) void transpose_f2b(
    const float* __restrict__ in, unsigned short* __restrict__ out,
    int R, int C)
{
    __shared__ unsigned short t[32][33];
    int tx = threadIdx.x, ty = threadIdx.y;       // (32,8)
    int c = blockIdx.x * 32 + tx;
#pragma unroll
    for (int i = 0; i < 4; ++i) {
        int r = blockIdx.y * 32 + ty + i * 8;
        t[ty + i * 8][tx] = f2b(in[(size_t)r * C + c]);
    }
    __syncthreads();
    int r2 = blockIdx.y * 32 + tx;
#pragma unroll
    for (int i = 0; i < 4; ++i) {
        int c2 = blockIdx.x * 32 + ty + i * 8;
        out[(size_t)c2 * R + r2] = t[tx][ty + i * 8];
    }
}

// ---- prep: Wq/Wkv transposes (f32->bf16, [R][C]->[C][R]) + null-kv -------
// bid<1024: Wq tile; 1024..3071: Wkv tile; 3072..3075: nullkv (k l2norm ->
// knull bf16; v f16 -> VtG col 2048; zero pad cols 2049..2055).
__global__ __launch_bounds__(256) void prep_kernel(
    const float* __restrict__ Wq, const float* __restrict__ Wkv,
    const float* __restrict__ null_kv, const float* __restrict__ k_scale,
    unsigned short* __restrict__ WqkvT, unsigned short* __restrict__ knull,
    unsigned short* __restrict__ Vt)
{
    __shared__ unsigned short t[32][33];
    const int bid = blockIdx.x;
    if (bid < 3072) {
        const float* in; unsigned short* out; int C, bx, by;
        if (bid < 1024) { in = Wq;  out = WqkvT;             C = 1024;
                          bx = bid & 31;  by = bid >> 5; }
        else            { int l = bid - 1024;
                          in = Wkv; out = WqkvT + (1u << 20); C = 2048;
                          bx = l & 63;    by = l >> 6; }
        int tx = threadIdx.x, ty = threadIdx.y;   // (32,8)
        int c = bx * 32 + tx;
#pragma unroll
        for (int i = 0; i < 4; ++i) {
            int r = by * 32 + ty + i * 8;
            t[ty + i * 8][tx] = f2b(in[(size_t)r * C + c]);
        }
        __syncthreads();
        int r2 = by * 32 + tx;
#pragma unroll
        for (int i = 0; i < 4; ++i) {
            int c2 = bx * 32 + ty + i * 8;
            out[(size_t)c2 * 1024 + r2] = t[tx][ty + i * 8];
        }
        return;
    }
    // ---- nullkv part (4 blocks, 256 flat threads each) ----
    const int nb = bid - 3072;
    int flat = threadIdx.x + threadIdx.y * 32;
    int wave = flat >> 6, lane = flat & 63;
    int h = nb * 4 + wave;
    int idx = (h << 6) + lane;
    float kvl = null_kv[idx];
    float ss = kvl * kvl;
#pragma unroll
    for (int off = 1; off < 64; off <<= 1) ss += __shfl_xor(ss, off);
    knull[idx] = f2b(kvl * rsqrtf(ss + 1e-12f) * k_scale[lane]);
    unsigned short vn = f2h(null_kv[1024 + idx]);
#pragma unroll
    for (int b = 0; b < 4; ++b)
        Vt[((size_t)(((b << 4) + h) << 6) + lane) * 2056 + 2048] = vn;
    int tt = nb * 256 + flat;                     // 0..1023
#pragma unroll
    for (int rr = 0; rr < 4; ++rr) {
        size_t row = (size_t)tt * 4 + rr;
#pragma unroll
        for (int c = 0; c < 7; ++c)
            Vt[row * 2056 + 2049 + c] = 0;
    }
}

// -------- LayerNorm: one row (1024 fp32) per block of 256 -> bf16 ----------
__global__ __launch_bounds__(256) void ln_kernel(
    const float* __restrict__ x, const float* __restrict__ gamma,
    unsigned short* __restrict__ xn)
{
    int row = blockIdx.x, tid = threadIdx.x;
    int wave = tid >> 6, lane = tid & 63;
    float4 raw = *(const float4*)(x + ((size_t)row << 10) + (tid << 2));
    float v[4] = { raw.x, raw.y, raw.z, raw.w };
    float s  = v[0] + v[1] + v[2] + v[3];
    float s2 = v[0]*v[0] + v[1]*v[1] + v[2]*v[2] + v[3]*v[3];
#pragma unroll
    for (int off = 1; off < 64; off <<= 1) {
        s  += __shfl_xor(s, off);
        s2 += __shfl_xor(s2, off);
    }
    __shared__ float ps[4], ps2[4], sh[2];
    if (lane == 0) { ps[wave] = s; ps2[wave] = s2; }
    __syncthreads();
    if (tid == 0) {
        float S  = ps[0] + ps[1] + ps[2] + ps[3];
        float S2 = ps2[0] + ps2[1] + ps2[2] + ps2[3];
        float mu  = S * (1.f / 1024.f);
        float var = S2 * (1.f / 1024.f) - mu * mu;
        sh[0] = mu; sh[1] = rsqrtf(var + 1e-5f);
    }
    __syncthreads();
    float mu = sh[0], rstd = sh[1];
    float4 g4 = *(const float4*)(gamma + (tid << 2));
    float g[4] = { g4.x, g4.y, g4.z, g4.w };
    unsigned short o[4];
#pragma unroll
    for (int i = 0; i < 4; ++i) o[i] = f2b((v[i] - mu) * rstd * g[i]);
    uint2 out;
    out.x = (unsigned)o[0] | ((unsigned)o[1] << 16);
    out.y = (unsigned)o[2] | ((unsigned)o[3] << 16);
    *(uint2*)(xn + ((size_t)row << 10) + (tid << 2)) = out;
}

// ---- GEMM C=A[8192,K]*Bt[N,K]^T, 128x128 tile, BK=64, swizzled dbuf LDS --
// 2-phase: stage(next, buf^1) -> compute(buf) -> ONE barrier per K-step.
// Tile mapping: local=bid&511 rotated to swz=(local&7)*64+(local>>3) so each
// XCD owns a contiguous band of 8 m-tiles (R16). LDS [row][64] granule g at
// slot g^(row&7), staged pre-swizzled; ds_read_b128 <=2-way.
// MODE 0: role=bid>>9: 0 Q l2norm*qs*0.125*log2e -> C0; 1 K l2norm*ks -> Ck;
//         2 V raw f16 transposed -> Vout (LDS tile aliases staging smem).
// MODE 2: 512 blocks, plain f32 store -> C0.
template<int MODE>
__global__ __launch_bounds__(256, 2) void gemm_bt(
    const unsigned short* __restrict__ A,
    const unsigned short* __restrict__ Bt,
    void* __restrict__ C0,
    unsigned short* __restrict__ Ck,
    unsigned short* __restrict__ Vout,
    const float* __restrict__ qs, const float* __restrict__ ks,
    int K)
{
    __shared__ __align__(16) unsigned char smem[65536];
    __bf16* As = (__bf16*)smem;             // [2][128][64] swizzled granules
    __bf16* Bs = (__bf16*)(smem + 32768);

    int tid = threadIdx.x, lane = tid & 63, wave = tid >> 6;
    int quad = lane >> 4, l15 = lane & 15;
    const int bid = blockIdx.x;
    const int role = bid >> 9;              // 0=Q 1=K 2=V (MODE 0)
    const int local = bid & 511;
    const int swztile = ((local & 7) << 6) | (local >> 3);  // XCD-chunked
    int m0 = (swztile >> 3) * 128;
    int n0 = role * 1024 + (swztile & 7) * 128;
    int wm = (wave & 1) * 64, wn = (wave >> 1) * 64;
    f32x4 acc[4][4] = {};

    // staging: lane covers row (slab + p*8 + lane>>3), granule (lane&7);
    // source col pre-swizzled so LDS slot w holds granule w^(row&7).
    const int srow8 = lane >> 3;            // row-within-8 == (row&7)
    const int w7    = lane & 7;
    const int swz   = ((w7 ^ srow8) << 3);  // halfs
    const unsigned short* gA = A  + (size_t)(m0 + wave * 32 + srow8) * K + swz;
    const unsigned short* gB = Bt + (size_t)(n0 + wave * 32 + srow8) * K + swz;
    const size_t r8 = (size_t)8 * K;

    auto stage = [&](int bf) {
        __bf16* Ab = As + bf * 8192;
        __bf16* Bb = Bs + bf * 8192;
#pragma unroll
        for (int p = 0; p < 4; ++p)
            gl_lds16(gA + p * r8, &Ab[(wave * 32 + p * 8) * 64]);
#pragma unroll
        for (int p = 0; p < 4; ++p)
            gl_lds16(gB + p * r8, &Bb[(wave * 32 + p * 8) * 64]);
        gA += 64; gB += 64;
    };

    stage(0);
    __syncthreads();                        // tile 0 resident
    const int nsteps = K >> 6;
    for (int s = 0; s < nsteps; ++s) {
        const int cur = s & 1;
        if (s + 1 < nsteps) stage(cur ^ 1); // prefetch flies under compute
        const __bf16* Ab = As + cur * 8192;
        const __bf16* Bb = Bs + cur * 8192;
#pragma unroll
        for (int kk = 0; kk < 2; ++kk) {
            bf16x8 af[4], bfv[4];
#pragma unroll
            for (int i = 0; i < 4; ++i) {
                int row = wm + i * 16 + l15;
                int g = ((kk << 2) + quad) ^ (l15 & 7);
                af[i] = *(const bf16x8*)&Ab[row * 64 + (g << 3)];
            }
#pragma unroll
            for (int j = 0; j < 4; ++j) {
                int row = wn + j * 16 + l15;
                int g = ((kk << 2) + quad) ^ (l15 & 7);
                bfv[j] = *(const bf16x8*)&Bb[row * 64 + (g << 3)];
            }
#pragma unroll
            for (int i = 0; i < 4; ++i)
#pragma unroll
                for (int j = 0; j < 4; ++j)
                    acc[i][j] = mfma16(af[i], bfv[j], acc[i][j]);
        }
        __syncthreads();  // drains prefetch (flew under MFMA) + frees cur
    }

    if (MODE == 2) {
#pragma unroll
        for (int i = 0; i < 4; ++i)
#pragma unroll
            for (int j = 0; j < 4; ++j) {
                int row = m0 + wm + i * 16 + quad * 4;
                int col = n0 + wn + j * 16 + l15;
                size_t base = (size_t)row * 1024 + col;
#pragma unroll
                for (int r = 0; r < 4; ++r)
                    ((float*)C0)[base + (size_t)r * 1024] = acc[i][j][r];
            }
        return;
    }

    // ----- fused QKV epilogues (wave's 64 cols = one head) -----
    if (n0 >= 2048) {
        // V: per-wave 64x64 (tok x d) -> LDS transpose (aliases staging smem;
        // safe: final K-loop barrier drained all reads) -> uint2 stores.
        unsigned short* tileL = (unsigned short*)smem + wave * 4096;
        int hv = (n0 + wn - 2048) >> 6;
        int bidx = m0 >> 11;                        // block never straddles
        int tok0w = (m0 + wm) & 2047;
        size_t vbase = (size_t)((((bidx << 4) + hv) << 6)) * 2056;
#pragma unroll
        for (int i = 0; i < 4; ++i)
#pragma unroll
            for (int j = 0; j < 4; ++j) {
                int d = j * 16 + l15;
                int tk = (i * 16 + quad * 4) ^ ((d & 7) << 3);
                unsigned u01 = (unsigned)f2h(acc[i][j][0])
                             | ((unsigned)f2h(acc[i][j][1]) << 16);
                unsigned u23 = (unsigned)f2h(acc[i][j][2])
                             | ((unsigned)f2h(acc[i][j][3]) << 16);
                *(unsigned*)&tileL[d * 64 + tk]     = u01;
                *(unsigned*)&tileL[d * 64 + tk + 2] = u23;
            }
        // same-wave read-out (compiler orders via lgkmcnt)
#pragma unroll
        for (int rrr = 0; rrr < 16; ++rrr) {
            int d = rrr * 4 + quad;
            uint2 val = *(const uint2*)
                &tileL[d * 64 + ((l15 * 4) ^ ((d & 7) << 3))];
            *(uint2*)(Vout + vbase + (size_t)d * 2056 + tok0w + l15 * 4) = val;
        }
        return;
    }

    const bool isQ = (n0 < 1024);
    float sc[4];
#pragma unroll
    for (int j = 0; j < 4; ++j) {
        float s = isQ ? qs[j * 16 + l15] : ks[j * 16 + l15];
        sc[j] = isQ ? s * (0.125f * 1.44269504088896f) : s;
    }
    unsigned short* outp = isQ ? (unsigned short*)C0 : Ck;
    const int coln0 = isQ ? n0 : (n0 - 1024);
#pragma unroll
    for (int i = 0; i < 4; ++i)
#pragma unroll
        for (int r = 0; r < 4; ++r) {
            float ss = 0.f;
#pragma unroll
            for (int j = 0; j < 4; ++j) ss += acc[i][j][r] * acc[i][j][r];
            ss += __shfl_xor(ss, 1); ss += __shfl_xor(ss, 2);
            ss += __shfl_xor(ss, 4); ss += __shfl_xor(ss, 8);
            float mul = rsqrtf(ss + 1e-12f);
            size_t rowbase = (size_t)(m0 + wm + i * 16 + quad * 4 + r) * 1024
                           + coln0 + wn + l15;
#pragma unroll
            for (int j = 0; j < 4; ++j) {
                float v = acc[i][j][r];
                outp[rowbase + j * 16] = f2b(v * mul * sc[j]);
            }
        }
}

// ---------------- attention: BM=128 (4 waves x 32 rows), BT=64 tokens ------
// (R13 structure; R17 adds setprio around the MFMA clusters)
__global__ __launch_bounds__(256, 4) void attn_kernel(
    const unsigned short* __restrict__ qn,    // [B*2048,1024] l2norm*qs*log2e/8
    const unsigned short* __restrict__ kvK,   // [B*2048,1024] k bf16 (l2norm)
    const unsigned short* __restrict__ knull, // [16*64] bf16
    const unsigned short* __restrict__ Vt,    // [64bh][64d][2056tok] f16
    const int* __restrict__ mask,             // [B*2048]
    unsigned short* __restrict__ ao)          // [B*2048,1024]
{
    __shared__ __bf16    Kt[2][64 * 64];
    __shared__ _Float16  Vl[2][64 * 64];
    __shared__ __align__(16) float biasLds[2][64];

    const int tid = threadIdx.x, lane = tid & 63, wave = tid >> 6;
    const int quad = lane >> 4, l15 = lane & 15;
    const int bh = blockIdx.x;                 // (b,h): K/V sharers same XCD
    const int b = bh >> 4, h = bh & 15;
    const int mbase = blockIdx.y * 128 + wave * 32;
    const size_t rowoff = (size_t)b * 2048;

    bf16x8 qf[2][2];                           // B-operand fragments
#pragma unroll
    for (int rg = 0; rg < 2; ++rg)
#pragma unroll
        for (int ks = 0; ks < 2; ++ks)
            qf[rg][ks] = *(const bf16x8*)
                &qn[((rowoff + mbase + rg * 16 + l15) << 10) + (h << 6) + ks * 32 + quad * 8];

    const int t8  = lane >> 3;
    const int w7  = lane & 7;
    const int ksc = (w7 ^ t8) << 3;            // (r&7)==t8 since base%8==0
    const size_t vrow0 = ((size_t)bh << 6);    // first VtG row of this (b,h)

    const int r0v = wave * 16 + t8;            // LDS row (p=0) = V d-row
    const int r1v = wave * 16 + 8 + t8;        // LDS row (p=1)
    auto Tof = [](int r) {
        return ((r >> 5) << 5) | (((r >> 2) & 3) << 3)
             | (((r >> 4) & 1) << 2) | (r & 3);
    };
    const int T0 = Tof(r0v), T1 = Tof(r1v);    // T1 != 0 always

    // strength-reduced staging pointers (point at NEXT tile to issue)
    const unsigned short* kp0 = kvK + ((rowoff + T0) << 10) + (h << 6) + ksc;
    const unsigned short* kp1 = kvK + ((rowoff + T1) << 10) + (h << 6) + ksc;
    const unsigned short* vp0 = Vt + (vrow0 + r0v) * 2056 + ((w7 ^ t8) << 3);
    const unsigned short* vp1 = Vt + (vrow0 + r1v) * 2056 + ((w7 ^ t8) << 3);

    auto issueFast = [&](int bf) {
        gl_lds16(kp0, &Kt[bf][(wave * 16) * 64]);
        gl_lds16(kp1, &Kt[bf][(wave * 16 + 8) * 64]);
        gl_lds16(vp0, &Vl[bf][(wave * 16) * 64]);
        gl_lds16(vp1, &Vl[bf][(wave * 16 + 8) * 64]);
        kp0 += 65536; kp1 += 65536;            // 64 tokens * 1024 halfs
        vp0 += 64; vp1 += 64;                  // 8 granules
    };
    auto issue32 = [&](int bf) {               // tokens 2048..2111
        const unsigned short* kc =
            kvK + ((rowoff + 2047) << 10) + (h << 6) + ksc;   // finite clamp
        const unsigned short* s0 = (T0 == 0) ? knull + (h << 6) + ksc : kc;
        gl_lds16(s0, &Kt[bf][(wave * 16) * 64]);
        gl_lds16(kc, &Kt[bf][(wave * 16 + 8) * 64]);
        gl_lds16(Vt + (vrow0 + r0v) * 2056 + 2048, &Vl[bf][(wave * 16) * 64]);
        gl_lds16(Vt + (vrow0 + r1v) * 2056 + 2048, &Vl[bf][(wave * 16 + 8) * 64]);
    };
    auto biasFor = [&](int nt) -> float {      // wave 0 only
        int j = (nt << 6) + lane;
        float bv = -512.f;
        if (j < 2048) { if (mask[(b << 11) + j] != 0) bv = 0.f; }
        else if (j == 2048) bv = 0.f;
        return bv;
    };

    const uintv4 onesu = { 0x3c003c00u, 0x3c003c00u, 0x3c003c00u, 0x3c003c00u };
    const f16x8 ones = __builtin_bit_cast(f16x8, onesu);

    f32x4 O[2][4] = {};
    f32x4 rsacc[2] = {};

    issueFast(0);
    float bcur = 0.f;
    if (wave == 0) bcur = biasFor(0);

    for (int nt = 0; nt < 33; ++nt) {
        const int buf = nt & 1;
        if (wave == 0) biasLds[buf][lane] = bcur;
        __syncthreads();   // drains gl_lds(nt); bias(nt) visible; prev buf free
        if (nt < 31) {     // issue AFTER barrier: overlaps compute below
            issueFast(buf ^ 1);
            if (wave == 0) bcur = biasFor(nt + 1);
        } else if (nt == 31) {
            issue32(buf ^ 1);
            if (wave == 0) bcur = biasFor(32);
        }

#pragma unroll
        for (int g = 0; g < 2; ++g) {
            // --- QK^T: only one kf pair (8 VGPRs) live at a time ---
            float4 b0 = *(const float4*)&biasLds[buf][(g << 5) + (quad << 3)];
            float4 b1 = *(const float4*)&biasLds[buf][(g << 5) + (quad << 3) + 4];
            f32x4 s[2][2];
#pragma unroll
            for (int rg = 0; rg < 2; ++rg) {
                s[rg][0] = f32x4{ b0.x, b0.y, b0.z, b0.w };
                s[rg][1] = f32x4{ b1.x, b1.y, b1.z, b1.w };
            }
#pragma unroll
            for (int t = 0; t < 2; ++t) {
                const __bf16* kb = &Kt[buf][((g * 2 + t) * 16 + l15) * 64];
                bf16x8 k0 = *(const bf16x8*)&kb[(quad ^ (l15 & 7)) << 3];
                bf16x8 k1 = *(const bf16x8*)&kb[((4 + quad) ^ (l15 & 7)) << 3];
                __builtin_amdgcn_s_setprio(1);
#pragma unroll
                for (int rg = 0; rg < 2; ++rg) {
                    s[rg][t] = mfma16(k0, qf[rg][0], s[rg][t]);
                    s[rg][t] = mfma16(k1, qf[rg][1], s[rg][t]);
                }
                __builtin_amdgcn_s_setprio(0);
            }
            // --- V fragments: one b128 each, XOR-swizzled slot ---
            f16x8 vf8[4];
#pragma unroll
            for (int dt = 0; dt < 4; ++dt)
                vf8[dt] = *(const f16x8*)
                    &Vl[buf][(dt * 16 + l15) * 64
                             + ((((g << 2) + quad) ^ (l15 & 7)) << 3)];
            // --- exp2 + pack + PV (+ denominator via ones-MFMA) ---
#pragma unroll
            for (int rg = 0; rg < 2; ++rg) {
                float e0 = __builtin_amdgcn_exp2f(s[rg][0][0]);
                float e1 = __builtin_amdgcn_exp2f(s[rg][0][1]);
                float e2 = __builtin_amdgcn_exp2f(s[rg][0][2]);
                float e3 = __builtin_amdgcn_exp2f(s[rg][0][3]);
                float e4 = __builtin_amdgcn_exp2f(s[rg][1][0]);
                float e5 = __builtin_amdgcn_exp2f(s[rg][1][1]);
                float e6 = __builtin_amdgcn_exp2f(s[rg][1][2]);
                float e7 = __builtin_amdgcn_exp2f(s[rg][1][3]);
                uintv4 pu = { pk16(e0, e1), pk16(e2, e3),
                              pk16(e4, e5), pk16(e6, e7) };
                f16x8 p = __builtin_bit_cast(f16x8, pu);
                __builtin_amdgcn_s_setprio(1);
                rsacc[rg] = mfma16h(p, ones, rsacc[rg]);
#pragma unroll
                for (int dt = 0; dt < 4; ++dt)
                    O[rg][dt] = mfma16h(p, vf8[dt], O[rg][dt]);
                __builtin_amdgcn_s_setprio(0);
            }
        }
    }

    // rsacc[rg][r] = denom for q-row rg*16 + quad*4 + r (same lane as O rows)
#pragma unroll
    for (int rg = 0; rg < 2; ++rg) {
        float inv[4];
#pragma unroll
        for (int r = 0; r < 4; ++r) inv[r] = 1.f / rsacc[rg][r];
#pragma unroll
        for (int dt = 0; dt < 4; ++dt) {
            size_t base = ((rowoff + mbase + rg * 16 + quad * 4) << 10)
                        + (h << 6) + dt * 16 + l15;
#pragma unroll
            for (int r = 0; r < 4; ++r)
                ao[base + ((size_t)r << 10)] = f2b(O[rg][dt][r] * inv[r]);
        }
    }
}

// ---------------------------------------------------------------------------
extern "C" void kernel_launch(void* const* d_in, const int* in_sizes, int n_in,
                              void* d_out, int out_size, void* d_ws, size_t ws_size,
                              hipStream_t stream)
{
    const float* x       = (const float*)d_in[0];
    const int*   mask    = (const int*)d_in[1];
    const float* gamma   = (const float*)d_in[2];
    const float* null_kv = (const float*)d_in[3];
    const float* Wq      = (const float*)d_in[4];
    const float* Wkv     = (const float*)d_in[5];
    const float* q_scale = (const float*)d_in[6];
    const float* k_scale = (const float*)d_in[7];
    const float* Wout    = (const float*)d_in[8];

    // Workspace map (~70.07 MiB; ao aliases xn; WoutT lives in the dead q
    // buffer, written by a transpose launched AFTER attn):
    //   0        xn/ao    16 MiB
    //   16 MiB   q        16 MiB   (post-attn: first 2 MiB reused as WoutT)
    //   32 MiB   kvK      16 MiB   [tok][1024] bf16
    //   48 MiB   VtG      16.0625 MiB = 4096 rows * 4112 B ([bh][d][2056] f16)
    //   +VtG     WqkvT    6 MiB    [3072][1024] bf16 (Wq rows 0..1023,
    //                              Wkv K rows 1024..2047, V rows 2048..3071)
    //   +6 MiB   knull    2 KiB
    char* ws = (char*)d_ws;
    const size_t VTG_OFF   = (size_t)48u << 20;
    const size_t VTG_SIZE  = (size_t)4096 * 4112;
    const size_t WQKV_OFF  = VTG_OFF + VTG_SIZE;
    const size_t WQKV_SIZE = (size_t)3072 * 1024 * 2;
    unsigned short* xn    = (unsigned short*)(ws);
    unsigned short* ao    = xn;                                    // reuse
    unsigned short* q     = (unsigned short*)(ws + ((size_t)16u << 20));
    unsigned short* WoutT = q;                                     // post-attn
    unsigned short* kvK   = (unsigned short*)(ws + ((size_t)32u << 20));
    unsigned short* VtG   = (unsigned short*)(ws + VTG_OFF);
    unsigned short* WqkvT = (unsigned short*)(ws + WQKV_OFF);
    unsigned short* knull = (unsigned short*)(ws + WQKV_OFF + WQKV_SIZE);

    // prep: Wq/Wkv transposes + nullkv in one dispatch (3076 blocks)
    prep_kernel<<<dim3(3076), dim3(32, 8), 0, stream>>>(
        Wq, Wkv, null_kv, k_scale, WqkvT, knull, VtG);

    ln_kernel<<<8192, 256, 0, stream>>>(x, gamma, xn);

    // fused QKV projection, role-ordered 1-D grid with per-role XCD-chunked
    // tile swizzle: Q (0..511) first, K, then V last -> K/V freshest for attn
    gemm_bt<0><<<dim3(1536), 256, 0, stream>>>(xn, WqkvT, q, kvK, VtG,
                                               q_scale, k_scale, 1024);

    attn_kernel<<<dim3(64, 16), 256, 0, stream>>>(q, kvK, knull, VtG, mask, ao);

    // q is dead now; put WoutT there and run the out-projection
    transpose_f2b<<<dim3(32, 32), dim3(32, 8), 0, stream>>>(Wout, WoutT, 1024, 1024);

    gemm_bt<2><<<dim3(512), 256, 0, stream>>>(ao, WoutT, d_out, nullptr, nullptr,
                                              nullptr, nullptr, 1024);
}